// Round 1
// baseline (3346.207 us; speedup 1.0000x reference)
//
#include <hip/hip_runtime.h>
#include <hip/hip_bf16.h>

// ---------- problem constants ----------
#define TT 4096L     // tokens
#define HH 4096L     // hidden
#define II 11008L    // intermediate
#define NSLOT 8

typedef short bf16x8 __attribute__((ext_vector_type(8)));
typedef float f32x4  __attribute__((ext_vector_type(4)));

// fp32 -> bf16 RNE
__device__ __forceinline__ unsigned short f2bf(float v) {
  union { float f; unsigned int u; } c; c.f = v;
  unsigned int u = c.u;
  u += 0x7fffu + ((u >> 16) & 1u);
  return (unsigned short)(u >> 16);
}

// async global->LDS, 16B per lane; lds must be the wave-uniform base
__device__ __forceinline__ void load_lds16(const void* g, void* lds) {
  __builtin_amdgcn_global_load_lds(
      (const __attribute__((address_space(1))) unsigned int*)g,
      (__attribute__((address_space(3))) unsigned int*)lds, 16, 0, 0);
}

// ---------- fp32 -> bf16 convert (memory-bound, float4 vectorized) ----------
__global__ __launch_bounds__(256) void cvt_bf16_kernel(
    const float* __restrict__ in, unsigned short* __restrict__ out, long n4) {
  long i = (long)blockIdx.x * blockDim.x + threadIdx.x;
  long stride = (long)gridDim.x * blockDim.x;
  for (; i < n4; i += stride) {
    float4 v = ((const float4*)in)[i];
    ushort4 o;
    o.x = f2bf(v.x); o.y = f2bf(v.y); o.z = f2bf(v.z); o.w = f2bf(v.w);
    ((ushort4*)out)[i] = o;
  }
}

// ---------- token bucketing by slot (single block) ----------
__global__ __launch_bounds__(256) void bucket_kernel(
    const int* __restrict__ tix, int* __restrict__ cnt,
    int* __restrict__ off, int* __restrict__ list) {
  __shared__ int lc[NSLOT], lo[NSLOT], pc[NSLOT];
  int tid = threadIdx.x;
  if (tid < NSLOT) { lc[tid] = 0; pc[tid] = 0; }
  __syncthreads();
  for (int t = tid; t < TT; t += 256) atomicAdd(&lc[tix[t]], 1);
  __syncthreads();
  if (tid == 0) {
    int s = 0;
    for (int i = 0; i < NSLOT; ++i) { lo[i] = s; s += lc[i]; }
  }
  __syncthreads();
  for (int t = tid; t < TT; t += 256) {
    int s = tix[t];
    int p = atomicAdd(&pc[s], 1);
    list[lo[s] + p] = t;
  }
  if (tid < NSLOT) { cnt[tid] = lc[tid]; off[tid] = lo[tid]; }
}

// ---------- adapter phase 1: inter_r/inter_f (scaled) per token, fp32 ----------
// grid (slot, chunk64); block 256 = 4 waves; wave w handles tokens w*16..+15,
// thread owns 4 weight rows (of 256 = rg|ru|fg|fu concat), acc[4][16].
__global__ __launch_bounds__(256) void adapter_inter_kernel(
    const float* __restrict__ x,
    const float* __restrict__ rg, const float* __restrict__ ru,
    const float* __restrict__ fg, const float* __restrict__ fu,
    const float* __restrict__ scales,
    const int* __restrict__ cnt, const int* __restrict__ off,
    const int* __restrict__ list, float* __restrict__ irout) {
  __shared__ char smem[65536];           // xs: first 32KB during K-loop; ep: 64KB after
  __shared__ int tl[64];
  int s = blockIdx.x, c = blockIdx.y;
  int n = cnt[s];
  if (c * 64 >= n) return;
  int base = off[s] + c * 64;
  int ntok = min(64, n - c * 64);
  int tid = threadIdx.x;
  if (tid < 64) tl[tid] = (tid < ntok) ? list[base + tid] : list[off[s]];
  __syncthreads();

  float* xs = (float*)smem;              // [64][128]
  int rgi = tid & 63, tg = tid >> 6;
  const float* wbase[4] = { rg + (size_t)s * 64 * HH, ru + (size_t)s * 64 * HH,
                            fg + (size_t)s * 64 * HH, fu + (size_t)s * 64 * HH };
  const float* wrow[4];
#pragma unroll
  for (int r = 0; r < 4; ++r) {
    int rr = rgi * 4 + r;
    wrow[r] = wbase[rr >> 6] + (size_t)(rr & 63) * HH;
  }

  float acc[4][16];
#pragma unroll
  for (int r = 0; r < 4; ++r)
#pragma unroll
    for (int t2 = 0; t2 < 16; ++t2) acc[r][t2] = 0.f;

  for (int k0 = 0; k0 < HH; k0 += 128) {
    __syncthreads();
    for (int f = tid; f < 64 * 32; f += 256) {    // 64 rows x 32 float4
      int tk = f >> 5, kq = f & 31;
      float4 v = *(const float4*)(x + (size_t)tl[tk] * HH + k0 + kq * 4);
      *(float4*)(xs + tk * 128 + kq * 4) = v;
    }
    __syncthreads();
    for (int kk = 0; kk < 128; kk += 4) {
      float4 w4[4];
#pragma unroll
      for (int r = 0; r < 4; ++r) w4[r] = *(const float4*)(wrow[r] + k0 + kk);
#pragma unroll
      for (int t2 = 0; t2 < 16; ++t2) {
        float4 xv = *(const float4*)(xs + (tg * 16 + t2) * 128 + kk);
#pragma unroll
        for (int r = 0; r < 4; ++r)
          acc[r][t2] += w4[r].x * xv.x + w4[r].y * xv.y +
                        w4[r].z * xv.z + w4[r].w * xv.w;
      }
    }
  }

  // exchange via LDS to pair gate/up rows
  float* ep = (float*)smem;              // [256 rows][64 tok]
  __syncthreads();
#pragma unroll
  for (int r = 0; r < 4; ++r)
#pragma unroll
    for (int t2 = 0; t2 < 16; ++t2)
      ep[(rgi * 4 + r) * 64 + tg * 16 + t2] = acc[r][t2];
  __syncthreads();
  float s0 = scales[s * 2], s1 = scales[s * 2 + 1];
  for (int v = tid; v < 64 * 128; v += 256) {
    int tk = v >> 7, nn = v & 127;
    if (tk >= ntok) continue;
    float g, u, sc;
    if (nn < 64) { g = ep[nn * 64 + tk];          u = ep[(64 + nn) * 64 + tk];  sc = s0; }
    else         { g = ep[(64 + nn) * 64 + tk];   u = ep[(128 + nn) * 64 + tk]; sc = s1; }
    // note: for nn>=64, rows are 128+(nn-64)=64+nn and 192+(nn-64)=128+nn
    float sv = g / (1.f + __expf(-g));
    irout[(size_t)tl[tk] * 128 + nn] = sv * u * sc;
  }
}

// ---------- adapter phase 2: out += ir @ [rd|fd]^T, fp32 ----------
// grid (slot, chunk64); weights (128 f32) resident in regs per h; ir reads wave-uniform.
__global__ __launch_bounds__(256) void adapter_down_kernel(
    const float* __restrict__ rd, const float* __restrict__ fd,
    const int* __restrict__ cnt, const int* __restrict__ off,
    const int* __restrict__ list, const float* __restrict__ ir,
    float* __restrict__ out) {
  int s = blockIdx.x, c = blockIdx.y;
  int n = cnt[s];
  if (c * 64 >= n) return;
  int base = off[s] + c * 64;
  int ntok = min(64, n - c * 64);
  __shared__ int tl[64];
  int tid = threadIdx.x;
  if (tid < 64 && tid < ntok) tl[tid] = list[base + tid];
  __syncthreads();
  const float* rdb = rd + (size_t)s * HH * 64;
  const float* fdb = fd + (size_t)s * HH * 64;
  for (int pass = 0; pass < 16; ++pass) {
    int h = pass * 256 + tid;
    float wr_[64], wf_[64];
#pragma unroll
    for (int nq = 0; nq < 16; ++nq) {
      float4 a = *(const float4*)(rdb + (size_t)h * 64 + nq * 4);
      wr_[nq * 4] = a.x; wr_[nq * 4 + 1] = a.y; wr_[nq * 4 + 2] = a.z; wr_[nq * 4 + 3] = a.w;
      float4 b = *(const float4*)(fdb + (size_t)h * 64 + nq * 4);
      wf_[nq * 4] = b.x; wf_[nq * 4 + 1] = b.y; wf_[nq * 4 + 2] = b.z; wf_[nq * 4 + 3] = b.w;
    }
    for (int tk = 0; tk < ntok; ++tk) {
      int t = tl[tk];
      const float* irp = ir + (size_t)t * 128;   // wave-uniform -> scalar loads
      float acc = 0.f;
#pragma unroll
      for (int nn = 0; nn < 64; ++nn) acc += wr_[nn] * irp[nn];
#pragma unroll
      for (int nn = 0; nn < 64; ++nn) acc += wf_[nn] * irp[64 + nn];
      out[(size_t)t * HH + h] += acc;
    }
  }
}

// ---------- GEMM1: inter = silu(x@gate^T) * (x@up^T), bf16 in, bf16 out ----------
// 128(M) x 64(N) tile, dual B panels (gate rows n0.., up rows I+n0..).
// 4 waves 2x2; wave tile 64x32 per matrix; 16x16x32 bf16 MFMA.
__global__ __launch_bounds__(256) void gemm1_swiglu_kernel(
    const unsigned short* __restrict__ Xb,   // [T][H]
    const unsigned short* __restrict__ GU,   // [2I][H]
    unsigned short* __restrict__ inter) {    // [T][I]
  __shared__ unsigned short sA[128 * 32];    // 8KB
  __shared__ unsigned short sBg[64 * 32];    // 4KB
  __shared__ unsigned short sBu[64 * 32];    // 4KB
  const int tid = threadIdx.x;
  const int m0 = blockIdx.y * 128;
  const int n0 = blockIdx.x * 64;
  const int w = tid >> 6, l = tid & 63, l16 = l & 15, lq = l >> 4;
  const int wr = (w >> 1) * 64, wc = (w & 1) * 32;

  f32x4 ag[4][2], au[4][2];
#pragma unroll
  for (int i = 0; i < 4; ++i)
#pragma unroll
    for (int j = 0; j < 2; ++j) { ag[i][j] = (f32x4)0.f; au[i][j] = (f32x4)0.f; }

  for (int k0 = 0; k0 < HH; k0 += 32) {
    // stage A (8KB = 2 rounds of 256 slots x 16B)
#pragma unroll
    for (int r = 0; r < 2; ++r) {
      int slot = tid + r * 256;
      int row = slot >> 2, q = slot & 3;
      load_lds16(Xb + (size_t)(m0 + row) * HH + k0 + q * 8,
                 (char*)sA + (size_t)(w * 64 + r * 256) * 16);
    }
    // stage Bg, Bu (4KB each = 1 round)
    {
      int row = tid >> 2, q = tid & 3;
      load_lds16(GU + (size_t)(n0 + row) * HH + k0 + q * 8,
                 (char*)sBg + (size_t)(w * 64) * 16);
      load_lds16(GU + (size_t)(II + n0 + row) * HH + k0 + q * 8,
                 (char*)sBu + (size_t)(w * 64) * 16);
    }
    __syncthreads();
    bf16x8 av[4], bg[2], bu[2];
#pragma unroll
    for (int i = 0; i < 4; ++i)
      av[i] = *(const bf16x8*)((const char*)sA + (wr + i * 16 + l16) * 64 + lq * 16);
#pragma unroll
    for (int j = 0; j < 2; ++j) {
      bg[j] = *(const bf16x8*)((const char*)sBg + (wc + j * 16 + l16) * 64 + lq * 16);
      bu[j] = *(const bf16x8*)((const char*)sBu + (wc + j * 16 + l16) * 64 + lq * 16);
    }
#pragma unroll
    for (int i = 0; i < 4; ++i)
#pragma unroll
      for (int j = 0; j < 2; ++j) {
        ag[i][j] = __builtin_amdgcn_mfma_f32_16x16x32_bf16(av[i], bg[j], ag[i][j], 0, 0, 0);
        au[i][j] = __builtin_amdgcn_mfma_f32_16x16x32_bf16(av[i], bu[j], au[i][j], 0, 0, 0);
      }
    __syncthreads();
  }
  // epilogue: silu(g)*u -> bf16.  D layout: col=l16, row=lq*4+r
#pragma unroll
  for (int i = 0; i < 4; ++i)
#pragma unroll
    for (int j = 0; j < 2; ++j)
#pragma unroll
      for (int r = 0; r < 4; ++r) {
        int m = wr + i * 16 + lq * 4 + r;
        int nn = wc + j * 16 + l16;
        float g = ag[i][j][r], u = au[i][j][r];
        float sv = g / (1.f + __expf(-g));
        inter[(size_t)(m0 + m) * II + n0 + nn] = f2bf(sv * u);
      }
}

// ---------- GEMM2: C[M][N] = A[M][K] @ B[N][K]^T  (m97-style 128x128) ----------
__global__ __launch_bounds__(256) void gemm_bt_kernel(
    const unsigned short* __restrict__ A, const unsigned short* __restrict__ B,
    float* __restrict__ C, int M, int N, long K) {
  __shared__ unsigned short sA[128 * 32];
  __shared__ unsigned short sB[128 * 32];
  const int tid = threadIdx.x;
  const int m0 = blockIdx.y * 128;
  const int n0 = blockIdx.x * 128;
  const int w = tid >> 6, l = tid & 63, l16 = l & 15, lq = l >> 4;
  const int wr = (w >> 1) * 64, wc = (w & 1) * 64;

  f32x4 acc[4][4];
#pragma unroll
  for (int i = 0; i < 4; ++i)
#pragma unroll
    for (int j = 0; j < 4; ++j) acc[i][j] = (f32x4)0.f;

  for (long k0 = 0; k0 < K; k0 += 32) {
#pragma unroll
    for (int r = 0; r < 2; ++r) {
      int slot = tid + r * 256;
      int row = slot >> 2, q = slot & 3;
      load_lds16(A + (size_t)(m0 + row) * K + k0 + q * 8,
                 (char*)sA + (size_t)(w * 64 + r * 256) * 16);
      load_lds16(B + (size_t)(n0 + row) * K + k0 + q * 8,
                 (char*)sB + (size_t)(w * 64 + r * 256) * 16);
    }
    __syncthreads();
    bf16x8 av[4], bv[4];
#pragma unroll
    for (int i = 0; i < 4; ++i) {
      av[i] = *(const bf16x8*)((const char*)sA + (wr + i * 16 + l16) * 64 + lq * 16);
      bv[i] = *(const bf16x8*)((const char*)sB + (wc + i * 16 + l16) * 64 + lq * 16);
    }
#pragma unroll
    for (int i = 0; i < 4; ++i)
#pragma unroll
      for (int j = 0; j < 4; ++j)
        acc[i][j] = __builtin_amdgcn_mfma_f32_16x16x32_bf16(av[i], bv[j], acc[i][j], 0, 0, 0);
    __syncthreads();
  }
#pragma unroll
  for (int i = 0; i < 4; ++i)
#pragma unroll
    for (int j = 0; j < 4; ++j)
#pragma unroll
      for (int r = 0; r < 4; ++r) {
        int m = wr + i * 16 + lq * 4 + r;
        int nn = wc + j * 16 + l16;
        C[(size_t)(m0 + m) * N + n0 + nn] = acc[i][j][r];
      }
}

// ---------- launcher ----------
extern "C" void kernel_launch(void* const* d_in, const int* in_sizes, int n_in,
                              void* d_out, int out_size, void* d_ws, size_t ws_size,
                              hipStream_t stream) {
  const float* x   = (const float*)d_in[0];
  const float* guw = (const float*)d_in[1];
  const float* dww = (const float*)d_in[2];
  const float* rg  = (const float*)d_in[3];
  const float* ru  = (const float*)d_in[4];
  const float* rd  = (const float*)d_in[5];
  const float* fg  = (const float*)d_in[6];
  const float* fu  = (const float*)d_in[7];
  const float* fd  = (const float*)d_in[8];
  const float* sc  = (const float*)d_in[9];
  const int*   tix = (const int*)d_in[10];
  float* out = (float*)d_out;
  char* ws = (char*)d_ws;

  size_t o = 0;
  unsigned short* xb    = (unsigned short*)(ws + o); o += (size_t)TT * HH * 2;
  unsigned short* gub   = (unsigned short*)(ws + o); o += (size_t)2 * II * HH * 2;
  unsigned short* dwb   = (unsigned short*)(ws + o); o += (size_t)HH * II * 2;
  unsigned short* inter = (unsigned short*)(ws + o); o += (size_t)TT * II * 2;
  float* irbuf          = (float*)(ws + o);          o += (size_t)TT * 128 * 4;
  int* cntp             = (int*)(ws + o);            o += 64;
  int* offp             = (int*)(ws + o);            o += 64;
  int* listp            = (int*)(ws + o);            o += (size_t)TT * 4;

  cvt_bf16_kernel<<<2048, 256, 0, stream>>>(x, xb, TT * HH / 4);
  cvt_bf16_kernel<<<2048, 256, 0, stream>>>(guw, gub, 2 * II * HH / 4);
  cvt_bf16_kernel<<<2048, 256, 0, stream>>>(dww, dwb, HH * II / 4);
  bucket_kernel<<<1, 256, 0, stream>>>(tix, cntp, offp, listp);
  adapter_inter_kernel<<<dim3(NSLOT, 64), 256, 0, stream>>>(
      x, rg, ru, fg, fu, sc, cntp, offp, listp, irbuf);
  gemm1_swiglu_kernel<<<dim3(II / 64, TT / 128), 256, 0, stream>>>(xb, gub, inter);
  gemm_bt_kernel<<<dim3(HH / 128, TT / 128), 256, 0, stream>>>(
      inter, dwb, out, (int)TT, (int)HH, II);
  adapter_down_kernel<<<dim3(NSLOT, 64), 256, 0, stream>>>(
      rd, fd, cntp, offp, listp, irbuf, out);
}

// Round 2
// 2171.493 us; speedup vs baseline: 1.5410x; 1.5410x over previous
//
#include <hip/hip_runtime.h>
#include <hip/hip_bf16.h>

#define TT 4096L
#define HH 4096L
#define II 11008L
#define NSLOT 8

typedef short bf16x8 __attribute__((ext_vector_type(8)));
typedef float f32x4  __attribute__((ext_vector_type(4)));

#define WAIT_VM6() asm volatile("s_waitcnt vmcnt(6)" ::: "memory")
#define WAIT_VM0() asm volatile("s_waitcnt vmcnt(0)" ::: "memory")
#define WAIT_LGKM0() asm volatile("s_waitcnt lgkmcnt(0)" ::: "memory")
#define SBAR() __builtin_amdgcn_s_barrier()
#define SCHED0() __builtin_amdgcn_sched_barrier(0)

__device__ __forceinline__ unsigned short f2bf(float v) {
  union { float f; unsigned int u; } c; c.f = v;
  unsigned int u = c.u;
  u += 0x7fffu + ((u >> 16) & 1u);
  return (unsigned short)(u >> 16);
}

__device__ __forceinline__ void load_lds16(const void* g, void* lds) {
  __builtin_amdgcn_global_load_lds(
      (const __attribute__((address_space(1))) unsigned int*)g,
      (__attribute__((address_space(3))) unsigned int*)lds, 16, 0, 0);
}

// ---------- fp32 -> bf16 convert ----------
__global__ __launch_bounds__(256) void cvt_bf16_kernel(
    const float* __restrict__ in, unsigned short* __restrict__ out, long n4) {
  long i = (long)blockIdx.x * blockDim.x + threadIdx.x;
  long stride = (long)gridDim.x * blockDim.x;
  for (; i < n4; i += stride) {
    float4 v = ((const float4*)in)[i];
    ushort4 o;
    o.x = f2bf(v.x); o.y = f2bf(v.y); o.z = f2bf(v.z); o.w = f2bf(v.w);
    ((ushort4*)out)[i] = o;
  }
}

// ---------- token bucketing ----------
__global__ __launch_bounds__(256) void bucket_kernel(
    const int* __restrict__ tix, int* __restrict__ cnt,
    int* __restrict__ off, int* __restrict__ list) {
  __shared__ int lc[NSLOT], lo[NSLOT], pc[NSLOT];
  int tid = threadIdx.x;
  if (tid < NSLOT) { lc[tid] = 0; pc[tid] = 0; }
  __syncthreads();
  for (int t = tid; t < TT; t += 256) atomicAdd(&lc[tix[t]], 1);
  __syncthreads();
  if (tid == 0) {
    int s = 0;
    for (int i = 0; i < NSLOT; ++i) { lo[i] = s; s += lc[i]; }
  }
  __syncthreads();
  for (int t = tid; t < TT; t += 256) {
    int s = tix[t];
    int p = atomicAdd(&pc[s], 1);
    list[lo[s] + p] = t;
  }
  if (tid < NSLOT) { cnt[tid] = lc[tid]; off[tid] = lo[tid]; }
}

// ---------- adapter phase 1: grid (slot, chunk64, part4) ----------
// part p = (adapter a = p>>1, neuron-half h = p&1): 32 neurons -> 64 weight rows.
// thread = row (tid&63) x token-quarter (tid>>6): acc[16].
__global__ __launch_bounds__(256) void adapter_inter_kernel(
    const float* __restrict__ x,
    const float* __restrict__ rg, const float* __restrict__ ru,
    const float* __restrict__ fg, const float* __restrict__ fu,
    const float* __restrict__ scales,
    const int* __restrict__ cnt, const int* __restrict__ off,
    const int* __restrict__ list, float* __restrict__ irout) {
  __shared__ float xs[64 * 128];   // 32KB; reused as ep[64][64] in epilogue
  __shared__ int tl[64];
  int s = blockIdx.x, c = blockIdx.y, p = blockIdx.z;
  int n = cnt[s];
  if (c * 64 >= n) return;
  int base = off[s] + c * 64;
  int ntok = min(64, n - c * 64);
  int tid = threadIdx.x;
  if (tid < 64) tl[tid] = (tid < ntok) ? list[base + tid] : list[off[s]];
  __syncthreads();
  int a = p >> 1, h = p & 1;
  const float* gb = (a ? fg : rg) + ((size_t)s * 64 + h * 32) * HH;
  const float* ub = (a ? fu : ru) + ((size_t)s * 64 + h * 32) * HH;
  int rr = tid & 63, tq = tid >> 6;
  const float* wrow = (rr < 32) ? (gb + (size_t)rr * HH) : (ub + (size_t)(rr - 32) * HH);

  float acc[16];
#pragma unroll
  for (int t2 = 0; t2 < 16; ++t2) acc[t2] = 0.f;

  for (int k0 = 0; k0 < HH; k0 += 128) {
    __syncthreads();
    for (int f = tid; f < 64 * 32; f += 256) {
      int tk = f >> 5, kq = f & 31;
      *(float4*)(xs + tk * 128 + kq * 4) =
          *(const float4*)(x + (size_t)tl[tk] * HH + k0 + kq * 4);
    }
    __syncthreads();
    for (int kk = 0; kk < 128; kk += 4) {
      float4 w4 = *(const float4*)(wrow + k0 + kk);
#pragma unroll
      for (int t2 = 0; t2 < 16; ++t2) {
        float4 xv = *(const float4*)(xs + (tq * 16 + t2) * 128 + kk);
        acc[t2] += w4.x * xv.x + w4.y * xv.y + w4.z * xv.z + w4.w * xv.w;
      }
    }
  }
  __syncthreads();
  float* ep = xs;                  // [64 rows][64 tok]
#pragma unroll
  for (int t2 = 0; t2 < 16; ++t2) ep[rr * 64 + tq * 16 + t2] = acc[t2];
  __syncthreads();
  float sc = scales[s * 2 + a];
  for (int v = tid; v < 32 * 64; v += 256) {
    int nn = v >> 6, tk = v & 63;
    if (tk >= ntok) continue;
    float g = ep[nn * 64 + tk], u = ep[(32 + nn) * 64 + tk];
    float sv = g / (1.f + __expf(-g));
    irout[(size_t)tl[tk] * 128 + a * 64 + h * 32 + nn] = sv * u * sc;
  }
}

// ---------- adapter phase 2: grid (slot, chunk64, hquarter4) ----------
__global__ __launch_bounds__(256) void adapter_down_kernel(
    const float* __restrict__ rd, const float* __restrict__ fd,
    const int* __restrict__ cnt, const int* __restrict__ off,
    const int* __restrict__ list, const float* __restrict__ ir,
    float* __restrict__ out) {
  int s = blockIdx.x, c = blockIdx.y, hq = blockIdx.z;
  int n = cnt[s];
  if (c * 64 >= n) return;
  int base = off[s] + c * 64;
  int ntok = min(64, n - c * 64);
  __shared__ int tl[64];
  int tid = threadIdx.x;
  if (tid < 64 && tid < ntok) tl[tid] = list[base + tid];
  __syncthreads();
  const float* rdb = rd + (size_t)s * HH * 64;
  const float* fdb = fd + (size_t)s * HH * 64;
  for (int pass = 0; pass < 4; ++pass) {
    int hh = hq * 1024 + pass * 256 + tid;
    float wr_[64], wf_[64];
#pragma unroll
    for (int nq = 0; nq < 16; ++nq) {
      float4 av = *(const float4*)(rdb + (size_t)hh * 64 + nq * 4);
      wr_[nq * 4] = av.x; wr_[nq * 4 + 1] = av.y; wr_[nq * 4 + 2] = av.z; wr_[nq * 4 + 3] = av.w;
      float4 bv = *(const float4*)(fdb + (size_t)hh * 64 + nq * 4);
      wf_[nq * 4] = bv.x; wf_[nq * 4 + 1] = bv.y; wf_[nq * 4 + 2] = bv.z; wf_[nq * 4 + 3] = bv.w;
    }
    for (int tk = 0; tk < ntok; ++tk) {
      int t = tl[tk];
      const float* irp = ir + (size_t)t * 128;
      float acc = 0.f;
#pragma unroll
      for (int nn = 0; nn < 64; ++nn) acc += wr_[nn] * irp[nn];
#pragma unroll
      for (int nn = 0; nn < 64; ++nn) acc += wf_[nn] * irp[64 + nn];
      out[(size_t)t * HH + hh] += acc;
    }
  }
}

// =====================================================================
// GEMM2: C[4096][4096] = inter[4096][11008] @ down_w[4096][11008]^T
// 256x256 tile, BK=64, 8 waves, 8-phase schedule, counted vmcnt(6),
// swizzled LDS (slot ^= row&7), dbuf 128 KiB.
// =====================================================================
__global__ __launch_bounds__(512, 2) void gemm2_8p_kernel(
    const unsigned short* __restrict__ A,
    const unsigned short* __restrict__ B,
    float* __restrict__ C) {
  extern __shared__ char lds[];
  const long K = II;
  const int NT = (int)(K >> 6);                // 172
  const int tid = threadIdx.x;
  const int w = tid >> 6, l = tid & 63, l16 = l & 15, lq = l >> 4;
  const int wm = w >> 2, wn = w & 3;
  const long m0 = (long)blockIdx.y * 256, n0 = (long)blockIdx.x * 256;
  const int wb = w * 1024;

  // stage sources: chunk c = r*512+tid; row=c>>3; slot=(c&7)^(row&7)
  const int srow = tid >> 3;
  const int sslot = (tid & 7) ^ (srow & 7);
  const unsigned short* sA00 = A + (m0 +       srow) * K + sslot * 8;
  const unsigned short* sA01 = A + (m0 +  64 + srow) * K + sslot * 8;
  const unsigned short* sA10 = A + (m0 + 128 + srow) * K + sslot * 8;
  const unsigned short* sA11 = A + (m0 + 192 + srow) * K + sslot * 8;
  const unsigned short* sB00 = B + (n0 +       srow) * K + sslot * 8;
  const unsigned short* sB01 = B + (n0 +  64 + srow) * K + sslot * 8;
  const unsigned short* sB10 = B + (n0 + 128 + srow) * K + sslot * 8;
  const unsigned short* sB11 = B + (n0 + 192 + srow) * K + sslot * 8;

#define G2_STAGE_A0(bb, kt) do { \
    load_lds16(sA00 + (long)(kt) * 64, lds + (bb) + wb); \
    load_lds16(sA01 + (long)(kt) * 64, lds + (bb) + 8192 + wb); } while (0)
#define G2_STAGE_A1(bb, kt) do { \
    load_lds16(sA10 + (long)(kt) * 64, lds + (bb) + 16384 + wb); \
    load_lds16(sA11 + (long)(kt) * 64, lds + (bb) + 24576 + wb); } while (0)
#define G2_STAGE_B0(bb, kt) do { \
    load_lds16(sB00 + (long)(kt) * 64, lds + (bb) + 32768 + wb); \
    load_lds16(sB01 + (long)(kt) * 64, lds + (bb) + 40960 + wb); } while (0)
#define G2_STAGE_B1(bb, kt) do { \
    load_lds16(sB10 + (long)(kt) * 64, lds + (bb) + 49152 + wb); \
    load_lds16(sB11 + (long)(kt) * 64, lds + (bb) + 57344 + wb); } while (0)

  const int sw = l16 & 7;
  const int aoff0 = (wm * 64 + l16) * 128 + ((0 + lq) ^ sw) * 16;
  const int aoff1 = (wm * 64 + l16) * 128 + ((4 + lq) ^ sw) * 16;
  const int boff0 = (wn * 32 + l16) * 128 + ((0 + lq) ^ sw) * 16;
  const int boff1 = (wn * 32 + l16) * 128 + ((4 + lq) ^ sw) * 16;

  f32x4 acc[2][2][4][2];
#pragma unroll
  for (int qm = 0; qm < 2; ++qm)
#pragma unroll
    for (int qn = 0; qn < 2; ++qn)
#pragma unroll
      for (int i = 0; i < 4; ++i)
#pragma unroll
        for (int j = 0; j < 2; ++j) acc[qm][qn][i][j] = (f32x4)0.f;

  // prologue: tile0 all; tile1 A0,B1,A1 (B0(1) comes at kt=0 phase 0)
  G2_STAGE_A0(0, 0); G2_STAGE_A1(0, 0); G2_STAGE_B0(0, 0); G2_STAGE_B1(0, 0);
  G2_STAGE_A0(65536, 1); G2_STAGE_B1(65536, 1); G2_STAGE_A1(65536, 1);
  WAIT_VM6();
  SBAR();

  bf16x8 af[4][2], bfr[2][2];
#define G2_MFMA(qm, qn) do { \
    __builtin_amdgcn_s_setprio(1); \
    _Pragma("unroll") for (int i = 0; i < 4; ++i) \
      _Pragma("unroll") for (int j = 0; j < 2; ++j) { \
        acc[qm][qn][i][j] = __builtin_amdgcn_mfma_f32_16x16x32_bf16(af[i][0], bfr[j][0], acc[qm][qn][i][j], 0, 0, 0); \
        acc[qm][qn][i][j] = __builtin_amdgcn_mfma_f32_16x16x32_bf16(af[i][1], bfr[j][1], acc[qm][qn][i][j], 0, 0, 0); } \
    __builtin_amdgcn_s_setprio(0); } while (0)

  for (int kt = 0; kt < NT; ++kt) {
    const int bb = (kt & 1) << 16;
    const int ob = bb ^ 65536;
    const char* Lb = lds + bb;
    // phase 0: q(0,0) — read A0+B0; stage B0(kt+1)
#pragma unroll
    for (int i = 0; i < 4; ++i) {
      af[i][0] = *(const bf16x8*)(Lb + aoff0 + i * 2048);
      af[i][1] = *(const bf16x8*)(Lb + aoff1 + i * 2048);
    }
#pragma unroll
    for (int j = 0; j < 2; ++j) {
      bfr[j][0] = *(const bf16x8*)(Lb + 32768 + boff0 + j * 2048);
      bfr[j][1] = *(const bf16x8*)(Lb + 32768 + boff1 + j * 2048);
    }
    if (kt + 1 < NT) G2_STAGE_B0(ob, kt + 1);
    SBAR(); WAIT_LGKM0(); SCHED0();
    G2_MFMA(0, 0);
    SCHED0(); SBAR();
    // phase 1: q(0,1) — read B1 (reuse A0); stage A0(kt+2)
#pragma unroll
    for (int j = 0; j < 2; ++j) {
      bfr[j][0] = *(const bf16x8*)(Lb + 49152 + boff0 + j * 2048);
      bfr[j][1] = *(const bf16x8*)(Lb + 49152 + boff1 + j * 2048);
    }
    if (kt + 2 < NT) G2_STAGE_A0(bb, kt + 2);
    SBAR(); WAIT_LGKM0(); SCHED0();
    G2_MFMA(0, 1);
    SCHED0(); SBAR();
    // phase 2: q(1,1) — read A1 (reuse B1); stage B1(kt+2)
#pragma unroll
    for (int i = 0; i < 4; ++i) {
      af[i][0] = *(const bf16x8*)(Lb + 16384 + aoff0 + i * 2048);
      af[i][1] = *(const bf16x8*)(Lb + 16384 + aoff1 + i * 2048);
    }
    if (kt + 2 < NT) G2_STAGE_B1(bb, kt + 2);
    SBAR(); WAIT_LGKM0(); SCHED0();
    G2_MFMA(1, 1);
    SCHED0(); SBAR();
    // phase 3: q(1,0) — read B0 (reuse A1); stage A1(kt+2); counted vmcnt
#pragma unroll
    for (int j = 0; j < 2; ++j) {
      bfr[j][0] = *(const bf16x8*)(Lb + 32768 + boff0 + j * 2048);
      bfr[j][1] = *(const bf16x8*)(Lb + 32768 + boff1 + j * 2048);
    }
    if (kt + 2 < NT) G2_STAGE_A1(bb, kt + 2);
    SBAR(); WAIT_LGKM0(); SCHED0();
    G2_MFMA(1, 0);
    SCHED0();
    if (kt + 2 < NT) { WAIT_VM6(); } else { WAIT_VM0(); }
    SBAR();
  }

#pragma unroll
  for (int qm = 0; qm < 2; ++qm)
#pragma unroll
    for (int qn = 0; qn < 2; ++qn)
#pragma unroll
      for (int i = 0; i < 4; ++i)
#pragma unroll
        for (int j = 0; j < 2; ++j)
#pragma unroll
          for (int r = 0; r < 4; ++r) {
            long m = m0 + qm * 128 + wm * 64 + i * 16 + lq * 4 + r;
            long nn = n0 + qn * 128 + wn * 32 + j * 16 + l16;
            C[m * HH + nn] = acc[qm][qn][i][j][r];
          }
#undef G2_STAGE_A0
#undef G2_STAGE_A1
#undef G2_STAGE_B0
#undef G2_STAGE_B1
#undef G2_MFMA
}

// =====================================================================
// GEMM1: inter = silu(X@gate^T)*(X@up^T), dual-B 8-phase.
// 256(M) x 128(N) tile, BK=64, 8 waves (2Mx4N), same schedule as gemm2.
// LDS/buf: A0@0 A1@16K Bg0@32K Bg1@40K Bu0@48K Bu1@56K (64KB) x dbuf.
// =====================================================================
__global__ __launch_bounds__(512, 2) void gemm1_8p_kernel(
    const unsigned short* __restrict__ X,    // [TT][HH]
    const unsigned short* __restrict__ GU,   // [2I][HH]
    unsigned short* __restrict__ inter) {    // [TT][II]
  extern __shared__ char lds[];
  const long K = HH;
  const int NT = (int)(K >> 6);              // 64
  const int tid = threadIdx.x;
  const int w = tid >> 6, l = tid & 63, l16 = l & 15, lq = l >> 4;
  const int wm = w >> 2, wn = w & 3;
  const long m0 = (long)blockIdx.y * 256, n0 = (long)blockIdx.x * 128;
  const int wb = w * 1024;

  const int srow = tid >> 3;
  const int sslot = (tid & 7) ^ (srow & 7);
  const unsigned short* sA00 = X + (m0 +       srow) * K + sslot * 8;
  const unsigned short* sA01 = X + (m0 +  64 + srow) * K + sslot * 8;
  const unsigned short* sA10 = X + (m0 + 128 + srow) * K + sslot * 8;
  const unsigned short* sA11 = X + (m0 + 192 + srow) * K + sslot * 8;
  const unsigned short* sBg0 = GU + (n0 +      srow) * K + sslot * 8;
  const unsigned short* sBg1 = GU + (n0 + 64 + srow) * K + sslot * 8;
  const unsigned short* sBu0 = GU + (II + n0 +      srow) * K + sslot * 8;
  const unsigned short* sBu1 = GU + (II + n0 + 64 + srow) * K + sslot * 8;

#define G1_STAGE_A0(bb, kt) do { \
    load_lds16(sA00 + (long)(kt) * 64, lds + (bb) + wb); \
    load_lds16(sA01 + (long)(kt) * 64, lds + (bb) + 8192 + wb); } while (0)
#define G1_STAGE_A1(bb, kt) do { \
    load_lds16(sA10 + (long)(kt) * 64, lds + (bb) + 16384 + wb); \
    load_lds16(sA11 + (long)(kt) * 64, lds + (bb) + 24576 + wb); } while (0)
#define G1_STAGE_B0(bb, kt) do { \
    load_lds16(sBg0 + (long)(kt) * 64, lds + (bb) + 32768 + wb); \
    load_lds16(sBu0 + (long)(kt) * 64, lds + (bb) + 49152 + wb); } while (0)
#define G1_STAGE_B1(bb, kt) do { \
    load_lds16(sBg1 + (long)(kt) * 64, lds + (bb) + 40960 + wb); \
    load_lds16(sBu1 + (long)(kt) * 64, lds + (bb) + 57344 + wb); } while (0)

  const int sw = l16 & 7;
  const int aoff0 = (wm * 64 + l16) * 128 + ((0 + lq) ^ sw) * 16;
  const int aoff1 = (wm * 64 + l16) * 128 + ((4 + lq) ^ sw) * 16;
  const int boff0 = (wn * 16 + l16) * 128 + ((0 + lq) ^ sw) * 16;
  const int boff1 = (wn * 16 + l16) * 128 + ((4 + lq) ^ sw) * 16;

  f32x4 ag[2][2][4], au[2][2][4];
#pragma unroll
  for (int qm = 0; qm < 2; ++qm)
#pragma unroll
    for (int qn = 0; qn < 2; ++qn)
#pragma unroll
      for (int i = 0; i < 4; ++i) { ag[qm][qn][i] = (f32x4)0.f; au[qm][qn][i] = (f32x4)0.f; }

  G1_STAGE_A0(0, 0); G1_STAGE_A1(0, 0); G1_STAGE_B0(0, 0); G1_STAGE_B1(0, 0);
  G1_STAGE_A0(65536, 1); G1_STAGE_B1(65536, 1); G1_STAGE_A1(65536, 1);
  WAIT_VM6();
  SBAR();

  bf16x8 af[4][2], bg[2], bu[2];
#define G1_MFMA(qm, qn) do { \
    __builtin_amdgcn_s_setprio(1); \
    _Pragma("unroll") for (int i = 0; i < 4; ++i) { \
      ag[qm][qn][i] = __builtin_amdgcn_mfma_f32_16x16x32_bf16(af[i][0], bg[0], ag[qm][qn][i], 0, 0, 0); \
      ag[qm][qn][i] = __builtin_amdgcn_mfma_f32_16x16x32_bf16(af[i][1], bg[1], ag[qm][qn][i], 0, 0, 0); \
      au[qm][qn][i] = __builtin_amdgcn_mfma_f32_16x16x32_bf16(af[i][0], bu[0], au[qm][qn][i], 0, 0, 0); \
      au[qm][qn][i] = __builtin_amdgcn_mfma_f32_16x16x32_bf16(af[i][1], bu[1], au[qm][qn][i], 0, 0, 0); } \
    __builtin_amdgcn_s_setprio(0); } while (0)

  for (int kt = 0; kt < NT; ++kt) {
    const int bb = (kt & 1) << 16;
    const int ob = bb ^ 65536;
    const char* Lb = lds + bb;
    // phase 0: q(0,0)
#pragma unroll
    for (int i = 0; i < 4; ++i) {
      af[i][0] = *(const bf16x8*)(Lb + aoff0 + i * 2048);
      af[i][1] = *(const bf16x8*)(Lb + aoff1 + i * 2048);
    }
    bg[0] = *(const bf16x8*)(Lb + 32768 + boff0);
    bg[1] = *(const bf16x8*)(Lb + 32768 + boff1);
    bu[0] = *(const bf16x8*)(Lb + 49152 + boff0);
    bu[1] = *(const bf16x8*)(Lb + 49152 + boff1);
    if (kt + 1 < NT) G1_STAGE_B0(ob, kt + 1);
    SBAR(); WAIT_LGKM0(); SCHED0();
    G1_MFMA(0, 0);
    SCHED0(); SBAR();
    // phase 1: q(0,1) — read Bg1/Bu1, reuse A0
    bg[0] = *(const bf16x8*)(Lb + 40960 + boff0);
    bg[1] = *(const bf16x8*)(Lb + 40960 + boff1);
    bu[0] = *(const bf16x8*)(Lb + 57344 + boff0);
    bu[1] = *(const bf16x8*)(Lb + 57344 + boff1);
    if (kt + 2 < NT) G1_STAGE_A0(bb, kt + 2);
    SBAR(); WAIT_LGKM0(); SCHED0();
    G1_MFMA(0, 1);
    SCHED0(); SBAR();
    // phase 2: q(1,1) — read A1, reuse B1
#pragma unroll
    for (int i = 0; i < 4; ++i) {
      af[i][0] = *(const bf16x8*)(Lb + 16384 + aoff0 + i * 2048);
      af[i][1] = *(const bf16x8*)(Lb + 16384 + aoff1 + i * 2048);
    }
    if (kt + 2 < NT) G1_STAGE_B1(bb, kt + 2);
    SBAR(); WAIT_LGKM0(); SCHED0();
    G1_MFMA(1, 1);
    SCHED0(); SBAR();
    // phase 3: q(1,0) — read B0, reuse A1, counted vmcnt
    bg[0] = *(const bf16x8*)(Lb + 32768 + boff0);
    bg[1] = *(const bf16x8*)(Lb + 32768 + boff1);
    bu[0] = *(const bf16x8*)(Lb + 49152 + boff0);
    bu[1] = *(const bf16x8*)(Lb + 49152 + boff1);
    if (kt + 2 < NT) G1_STAGE_A1(bb, kt + 2);
    SBAR(); WAIT_LGKM0(); SCHED0();
    G1_MFMA(1, 0);
    SCHED0();
    if (kt + 2 < NT) { WAIT_VM6(); } else { WAIT_VM0(); }
    SBAR();
  }

#pragma unroll
  for (int qm = 0; qm < 2; ++qm)
#pragma unroll
    for (int qn = 0; qn < 2; ++qn)
#pragma unroll
      for (int i = 0; i < 4; ++i)
#pragma unroll
        for (int r = 0; r < 4; ++r) {
          long m = m0 + qm * 128 + wm * 64 + i * 16 + lq * 4 + r;
          long nn = n0 + qn * 64 + wn * 16 + l16;
          float g = ag[qm][qn][i][r], u = au[qm][qn][i][r];
          float sv = g / (1.f + __expf(-g));
          inter[m * II + nn] = f2bf(sv * u);
        }
#undef G1_STAGE_A0
#undef G1_STAGE_A1
#undef G1_STAGE_B0
#undef G1_STAGE_B1
#undef G1_MFMA
}

// ---------- launcher ----------
extern "C" void kernel_launch(void* const* d_in, const int* in_sizes, int n_in,
                              void* d_out, int out_size, void* d_ws, size_t ws_size,
                              hipStream_t stream) {
  const float* x   = (const float*)d_in[0];
  const float* guw = (const float*)d_in[1];
  const float* dww = (const float*)d_in[2];
  const float* rg  = (const float*)d_in[3];
  const float* ru  = (const float*)d_in[4];
  const float* rd  = (const float*)d_in[5];
  const float* fg  = (const float*)d_in[6];
  const float* fu  = (const float*)d_in[7];
  const float* fd  = (const float*)d_in[8];
  const float* sc  = (const float*)d_in[9];
  const int*   tix = (const int*)d_in[10];
  float* out = (float*)d_out;
  char* ws = (char*)d_ws;

  size_t o = 0;
  unsigned short* xb    = (unsigned short*)(ws + o); o += (size_t)TT * HH * 2;
  unsigned short* gub   = (unsigned short*)(ws + o); o += (size_t)2 * II * HH * 2;
  unsigned short* dwb   = (unsigned short*)(ws + o); o += (size_t)HH * II * 2;
  unsigned short* inter = (unsigned short*)(ws + o); o += (size_t)TT * II * 2;
  float* irbuf          = (float*)(ws + o);          o += (size_t)TT * 128 * 4;
  int* cntp             = (int*)(ws + o);            o += 64;
  int* offp             = (int*)(ws + o);            o += 64;
  int* listp            = (int*)(ws + o);            o += (size_t)TT * 4;

  static bool attr_set = false;
  (void)attr_set;
  hipFuncSetAttribute((const void*)gemm1_8p_kernel,
                      hipFuncAttributeMaxDynamicSharedMemorySize, 131072);
  hipFuncSetAttribute((const void*)gemm2_8p_kernel,
                      hipFuncAttributeMaxDynamicSharedMemorySize, 131072);

  cvt_bf16_kernel<<<2048, 256, 0, stream>>>(x, xb, TT * HH / 4);
  cvt_bf16_kernel<<<2048, 256, 0, stream>>>(guw, gub, 2 * II * HH / 4);
  cvt_bf16_kernel<<<2048, 256, 0, stream>>>(dww, dwb, HH * II / 4);
  bucket_kernel<<<1, 256, 0, stream>>>(tix, cntp, offp, listp);
  adapter_inter_kernel<<<dim3(NSLOT, 64, 4), 256, 0, stream>>>(
      x, rg, ru, fg, fu, sc, cntp, offp, listp, irbuf);
  gemm1_8p_kernel<<<dim3(II / 128, TT / 256), 512, 131072, stream>>>(xb, gub, inter);
  gemm2_8p_kernel<<<dim3(HH / 256, TT / 256), 512, 131072, stream>>>(inter, dwb, out);
  adapter_down_kernel<<<dim3(NSLOT, 64, 4), 256, 0, stream>>>(
      rd, fd, cntp, offp, listp, irbuf, out);
}

// Round 3
// 1242.064 us; speedup vs baseline: 2.6941x; 1.7483x over previous
//
#include <hip/hip_runtime.h>
#include <hip/hip_bf16.h>

#define TT 4096L
#define HH 4096L
#define II 11008L
#define NSLOT 8

typedef short bf16x8 __attribute__((ext_vector_type(8)));
typedef float f32x4  __attribute__((ext_vector_type(4)));

#define WAIT_VM6() asm volatile("s_waitcnt vmcnt(6)" ::: "memory")
#define WAIT_VM0() asm volatile("s_waitcnt vmcnt(0)" ::: "memory")
#define WAIT_LGKM0() asm volatile("s_waitcnt lgkmcnt(0)" ::: "memory")
#define SBAR() __builtin_amdgcn_s_barrier()
#define SCHED0() __builtin_amdgcn_sched_barrier(0)

__device__ __forceinline__ unsigned short f2bf(float v) {
  union { float f; unsigned int u; } c; c.f = v;
  unsigned int u = c.u;
  u += 0x7fffu + ((u >> 16) & 1u);
  return (unsigned short)(u >> 16);
}

__device__ __forceinline__ void load_lds16(const void* g, void* lds) {
  __builtin_amdgcn_global_load_lds(
      (const __attribute__((address_space(1))) unsigned int*)g,
      (__attribute__((address_space(3))) unsigned int*)lds, 16, 0, 0);
}

// ---------- fp32 -> bf16 convert ----------
__global__ __launch_bounds__(256) void cvt_bf16_kernel(
    const float* __restrict__ in, unsigned short* __restrict__ out, long n4) {
  long i = (long)blockIdx.x * blockDim.x + threadIdx.x;
  long stride = (long)gridDim.x * blockDim.x;
  for (; i < n4; i += stride) {
    float4 v = ((const float4*)in)[i];
    ushort4 o;
    o.x = f2bf(v.x); o.y = f2bf(v.y); o.z = f2bf(v.z); o.w = f2bf(v.w);
    ((ushort4*)out)[i] = o;
  }
}

// ---------- pack adapter up/gate weights: wab[s][256][H] bf16 ----------
// rows 0-63 = rg, 64-127 = ru, 128-191 = fg, 192-255 = fu
__global__ __launch_bounds__(256) void cvt_wab_kernel(
    const float* __restrict__ rg, const float* __restrict__ ru,
    const float* __restrict__ fg, const float* __restrict__ fu,
    unsigned short* __restrict__ wab) {
  const long N4 = 8L * 256 * HH / 4;
  long i = (long)blockIdx.x * blockDim.x + threadIdx.x;
  long stride = (long)gridDim.x * blockDim.x;
  for (; i < N4; i += stride) {
    long grow = i >> 10;             // H/4 = 1024 float4 per row
    long q = i & 1023;
    int s = (int)(grow >> 8), r = (int)(grow & 255);
    const float* src;
    int rr = r & 63;
    if (r < 64) src = rg; else if (r < 128) src = ru;
    else if (r < 192) src = fg; else src = fu;
    float4 v = ((const float4*)src)[((long)s * 64 + rr) * 1024 + q];
    ushort4 o;
    o.x = f2bf(v.x); o.y = f2bf(v.y); o.z = f2bf(v.z); o.w = f2bf(v.w);
    ((ushort4*)wab)[i] = o;
  }
}

// ---------- pack adapter down weights: wdb[s][H][128] bf16 (rd|fd) ----------
__global__ __launch_bounds__(256) void cvt_wdb_kernel(
    const float* __restrict__ rd, const float* __restrict__ fd,
    unsigned short* __restrict__ wdb) {
  const long N4 = 8L * HH * 128 / 4;
  long i = (long)blockIdx.x * blockDim.x + threadIdx.x;
  long stride = (long)gridDim.x * blockDim.x;
  for (; i < N4; i += stride) {
    long rowg = i >> 5;              // 128/4 = 32 float4 per out row
    int q = (int)(i & 31);
    float4 v;
    if (q < 16) v = ((const float4*)rd)[rowg * 16 + q];
    else        v = ((const float4*)fd)[rowg * 16 + (q - 16)];
    ushort4 o;
    o.x = f2bf(v.x); o.y = f2bf(v.y); o.z = f2bf(v.z); o.w = f2bf(v.w);
    ((ushort4*)wdb)[i] = o;
  }
}

// ---------- token bucketing ----------
__global__ __launch_bounds__(256) void bucket_kernel(
    const int* __restrict__ tix, int* __restrict__ cnt,
    int* __restrict__ off, int* __restrict__ list) {
  __shared__ int lc[NSLOT], lo[NSLOT], pc[NSLOT];
  int tid = threadIdx.x;
  if (tid < NSLOT) { lc[tid] = 0; pc[tid] = 0; }
  __syncthreads();
  for (int t = tid; t < TT; t += 256) atomicAdd(&lc[tix[t]], 1);
  __syncthreads();
  if (tid == 0) {
    int s = 0;
    for (int i = 0; i < NSLOT; ++i) { lo[i] = s; s += lc[i]; }
  }
  __syncthreads();
  for (int t = tid; t < TT; t += 256) {
    int s = tix[t];
    int p = atomicAdd(&pc[s], 1);
    list[lo[s] + p] = t;
  }
  if (tid < NSLOT) { cnt[tid] = lc[tid]; off[tid] = lo[tid]; }
}

// =====================================================================
// Adapter phase 1 (MFMA, split-K=4): psum[kq][t][256] = X[t] @ wab[s]^T
// grid (slot, chunk64, kq); 512 thr = 8 waves; M=64 gathered, N=256, BK=64.
// LDS per buf: sX[64][64] @0 (8KB), sW[256][64] @8192 (32KB); dbuf 80KB.
// =====================================================================
__global__ __launch_bounds__(512) void adapter_psum_kernel(
    const unsigned short* __restrict__ xb, const unsigned short* __restrict__ wab,
    const int* __restrict__ cnt, const int* __restrict__ off,
    const int* __restrict__ list, float* __restrict__ psum) {
  extern __shared__ char lds[];
  __shared__ int tl[64];
  int s = blockIdx.x, c = blockIdx.y, kq = blockIdx.z;
  int n = cnt[s];
  if (c * 64 >= n) return;
  int base = off[s] + c * 64;
  int ntok = min(64, n - c * 64);
  int tid = threadIdx.x;
  if (tid < 64) tl[tid] = (tid < ntok) ? list[base + tid] : list[base];
  __syncthreads();
  const int w = tid >> 6, l = tid & 63, l16 = l & 15, lq = l >> 4;
  const int sslot = (tid & 7) ^ ((tid >> 3) & 7);
  const long kbase = (long)kq * 1024;
  // X: 1 round (512 chunks), row = tid>>3 (0..63)
  const unsigned short* xsrc = xb + (size_t)tl[tid >> 3] * HH + kbase + sslot * 8;
  // W: 4 rounds, rows r*64 + tid>>3
  const unsigned short* wsrc = wab + ((size_t)s * 256 + (tid >> 3)) * HH + kbase + sslot * 8;
  const int wdst = w * 1024;

#define PS_STAGE(buf, t) do { \
    load_lds16(xsrc + (long)(t) * 64, lds + (buf) + wdst); \
    _Pragma("unroll") for (int r = 0; r < 4; ++r) \
      load_lds16(wsrc + (size_t)(r * 64) * HH + (long)(t) * 64, \
                 lds + (buf) + 8192 + r * 8192 + wdst); } while (0)

  const int sw = l16 & 7;
  f32x4 acc[4][2];
#pragma unroll
  for (int i = 0; i < 4; ++i)
#pragma unroll
    for (int j = 0; j < 2; ++j) acc[i][j] = (f32x4)0.f;

  PS_STAGE(0, 0);
  __syncthreads();
  for (int t = 0; t < 16; ++t) {
    const int cb = (t & 1) * 40960;
    if (t + 1 < 16) PS_STAGE(cb ^ 40960, t + 1);
    const char* Lb = lds + cb;
    bf16x8 av[4][2], bv[2][2];
#pragma unroll
    for (int i = 0; i < 4; ++i)
#pragma unroll
      for (int kh = 0; kh < 2; ++kh)
        av[i][kh] = *(const bf16x8*)(Lb + (i * 16 + l16) * 128 + (((kh * 4 + lq) ^ sw) * 16));
#pragma unroll
    for (int j = 0; j < 2; ++j)
#pragma unroll
      for (int kh = 0; kh < 2; ++kh)
        bv[j][kh] = *(const bf16x8*)(Lb + 8192 + (w * 32 + j * 16 + l16) * 128 + (((kh * 4 + lq) ^ sw) * 16));
#pragma unroll
    for (int i = 0; i < 4; ++i)
#pragma unroll
      for (int j = 0; j < 2; ++j) {
        acc[i][j] = __builtin_amdgcn_mfma_f32_16x16x32_bf16(av[i][0], bv[j][0], acc[i][j], 0, 0, 0);
        acc[i][j] = __builtin_amdgcn_mfma_f32_16x16x32_bf16(av[i][1], bv[j][1], acc[i][j], 0, 0, 0);
      }
    __syncthreads();
  }
  float* pb = psum + (size_t)kq * TT * 256;
#pragma unroll
  for (int i = 0; i < 4; ++i)
#pragma unroll
    for (int j = 0; j < 2; ++j)
#pragma unroll
      for (int r = 0; r < 4; ++r) {
        int tk = i * 16 + lq * 4 + r;
        pb[(size_t)tl[tk] * 256 + w * 32 + j * 16 + l16] = acc[i][j][r];
      }
#undef PS_STAGE
}

// ---------- reduce split-K + SwiGLU + scale -> irb bf16 [T][128] ----------
__global__ __launch_bounds__(256) void adapter_reduce_kernel(
    const float* __restrict__ psum, const float* __restrict__ scales,
    const int* __restrict__ tix, unsigned short* __restrict__ irb) {
  int idx = blockIdx.x * 256 + threadIdx.x;     // T*128 = 524288 total
  int t = idx >> 7, n = idx & 127;
  int a = n >> 6, nn = n & 63;
  int cg = a ? 128 + nn : nn;
  size_t b = (size_t)t * 256;
  float g = 0.f, u = 0.f;
#pragma unroll
  for (int kq = 0; kq < 4; ++kq) {
    g += psum[(size_t)kq * TT * 256 + b + cg];
    u += psum[(size_t)kq * TT * 256 + b + cg + 64];
  }
  float sc = scales[tix[t] * 2 + a];
  float sv = g / (1.f + __expf(-g));
  irb[idx] = f2bf(sv * u * sc);
}

// =====================================================================
// Adapter phase 2 (MFMA): out[t][h] += irb[t][:] @ wdb[s][h][:]^T
// grid (slot, chunk64, hblk16); 512 thr; M=64, N=256, K=128 single shot.
// LDS: sIr[64][128] @0 (16KB), sW[256][128] @16384 (64KB).
// =====================================================================
__global__ __launch_bounds__(512) void adapter_down2_kernel(
    const unsigned short* __restrict__ irb, const unsigned short* __restrict__ wdb,
    const int* __restrict__ cnt, const int* __restrict__ off,
    const int* __restrict__ list, float* __restrict__ out) {
  extern __shared__ char lds[];
  __shared__ int tl[64];
  int s = blockIdx.x, c = blockIdx.y, hb = blockIdx.z;
  int n = cnt[s];
  if (c * 64 >= n) return;
  int base = off[s] + c * 64;
  int ntok = min(64, n - c * 64);
  int tid = threadIdx.x;
  if (tid < 64) tl[tid] = (tid < ntok) ? list[base + tid] : list[base];
  __syncthreads();
  const int w = tid >> 6, l = tid & 63, l16 = l & 15, lq = l >> 4;
  const int sslot = (tid & 15) ^ ((tid >> 4) & 15);
  const int wdst = w * 1024;
  // sIr: 2 rounds, rows r*32 + tid>>4
  const unsigned short* isrc0 = irb + (size_t)tl[tid >> 4] * 128 + sslot * 8;
  const unsigned short* isrc1 = irb + (size_t)tl[32 + (tid >> 4)] * 128 + sslot * 8;
  // sW: 8 rounds, rows r*32 + tid>>4 within h-block
  const unsigned short* wsrc =
      wdb + ((size_t)s * HH + hb * 256 + (tid >> 4)) * 128 + sslot * 8;
  load_lds16(isrc0, lds + wdst);
  load_lds16(isrc1, lds + 8192 + wdst);
#pragma unroll
  for (int r = 0; r < 8; ++r)
    load_lds16(wsrc + (size_t)r * 4096, lds + 16384 + r * 8192 + wdst);
  __syncthreads();

  f32x4 acc[4][2];
#pragma unroll
  for (int i = 0; i < 4; ++i)
#pragma unroll
    for (int j = 0; j < 2; ++j) acc[i][j] = (f32x4)0.f;

#pragma unroll
  for (int kf = 0; kf < 4; ++kf) {
    bf16x8 av[4], bv[2];
#pragma unroll
    for (int i = 0; i < 4; ++i)
      av[i] = *(const bf16x8*)(lds + (i * 16 + l16) * 256 + (((kf * 4 + lq) ^ l16) * 16));
#pragma unroll
    for (int j = 0; j < 2; ++j)
      bv[j] = *(const bf16x8*)(lds + 16384 + (w * 32 + j * 16 + l16) * 256 + (((kf * 4 + lq) ^ l16) * 16));
#pragma unroll
    for (int i = 0; i < 4; ++i)
#pragma unroll
      for (int j = 0; j < 2; ++j)
        acc[i][j] = __builtin_amdgcn_mfma_f32_16x16x32_bf16(av[i], bv[j], acc[i][j], 0, 0, 0);
  }
#pragma unroll
  for (int i = 0; i < 4; ++i)
#pragma unroll
    for (int j = 0; j < 2; ++j)
#pragma unroll
      for (int r = 0; r < 4; ++r) {
        int tk = i * 16 + lq * 4 + r;
        if (tk < ntok) {
          size_t o = (size_t)tl[tk] * HH + hb * 256 + w * 32 + j * 16 + l16;
          out[o] += acc[i][j][r];
        }
      }
}

// =====================================================================
// GEMM2: C = inter @ down_w^T — 256x256, BK=64, 8-phase, vmcnt(6), XCD swz
// =====================================================================
__global__ __launch_bounds__(512, 2) void gemm2_8p_kernel(
    const unsigned short* __restrict__ A,
    const unsigned short* __restrict__ B,
    float* __restrict__ C) {
  extern __shared__ char lds[];
  const long K = II;
  const int NT = (int)(K >> 6);
  const int tid = threadIdx.x;
  const int w = tid >> 6, l = tid & 63, l16 = l & 15, lq = l >> 4;
  const int wm = w >> 2, wn = w & 3;
  const int lin = blockIdx.y * 16 + blockIdx.x;      // nwg=256
  const int l2 = (lin & 7) * 32 + (lin >> 3);
  const long m0 = (long)(l2 >> 4) * 256, n0 = (long)(l2 & 15) * 256;
  const int wb = w * 1024;

  const int srow = tid >> 3;
  const int sslot = (tid & 7) ^ (srow & 7);
  const unsigned short* sA00 = A + (m0 +       srow) * K + sslot * 8;
  const unsigned short* sA01 = A + (m0 +  64 + srow) * K + sslot * 8;
  const unsigned short* sA10 = A + (m0 + 128 + srow) * K + sslot * 8;
  const unsigned short* sA11 = A + (m0 + 192 + srow) * K + sslot * 8;
  const unsigned short* sB00 = B + (n0 +       srow) * K + sslot * 8;
  const unsigned short* sB01 = B + (n0 +  64 + srow) * K + sslot * 8;
  const unsigned short* sB10 = B + (n0 + 128 + srow) * K + sslot * 8;
  const unsigned short* sB11 = B + (n0 + 192 + srow) * K + sslot * 8;

#define G2_STAGE_A0(bb, kt) do { \
    load_lds16(sA00 + (long)(kt) * 64, lds + (bb) + wb); \
    load_lds16(sA01 + (long)(kt) * 64, lds + (bb) + 8192 + wb); } while (0)
#define G2_STAGE_A1(bb, kt) do { \
    load_lds16(sA10 + (long)(kt) * 64, lds + (bb) + 16384 + wb); \
    load_lds16(sA11 + (long)(kt) * 64, lds + (bb) + 24576 + wb); } while (0)
#define G2_STAGE_B0(bb, kt) do { \
    load_lds16(sB00 + (long)(kt) * 64, lds + (bb) + 32768 + wb); \
    load_lds16(sB01 + (long)(kt) * 64, lds + (bb) + 40960 + wb); } while (0)
#define G2_STAGE_B1(bb, kt) do { \
    load_lds16(sB10 + (long)(kt) * 64, lds + (bb) + 49152 + wb); \
    load_lds16(sB11 + (long)(kt) * 64, lds + (bb) + 57344 + wb); } while (0)

  const int sw = l16 & 7;
  const int aoff0 = (wm * 64 + l16) * 128 + ((0 + lq) ^ sw) * 16;
  const int aoff1 = (wm * 64 + l16) * 128 + ((4 + lq) ^ sw) * 16;
  const int boff0 = (wn * 32 + l16) * 128 + ((0 + lq) ^ sw) * 16;
  const int boff1 = (wn * 32 + l16) * 128 + ((4 + lq) ^ sw) * 16;

  f32x4 acc[2][2][4][2];
#pragma unroll
  for (int qm = 0; qm < 2; ++qm)
#pragma unroll
    for (int qn = 0; qn < 2; ++qn)
#pragma unroll
      for (int i = 0; i < 4; ++i)
#pragma unroll
        for (int j = 0; j < 2; ++j) acc[qm][qn][i][j] = (f32x4)0.f;

  G2_STAGE_A0(0, 0); G2_STAGE_A1(0, 0); G2_STAGE_B0(0, 0); G2_STAGE_B1(0, 0);
  G2_STAGE_A0(65536, 1); G2_STAGE_B1(65536, 1); G2_STAGE_A1(65536, 1);
  WAIT_VM6();
  SBAR();

  bf16x8 af[4][2], bfr[2][2];
#define G2_MFMA(qm, qn) do { \
    __builtin_amdgcn_s_setprio(1); \
    _Pragma("unroll") for (int i = 0; i < 4; ++i) \
      _Pragma("unroll") for (int j = 0; j < 2; ++j) { \
        acc[qm][qn][i][j] = __builtin_amdgcn_mfma_f32_16x16x32_bf16(af[i][0], bfr[j][0], acc[qm][qn][i][j], 0, 0, 0); \
        acc[qm][qn][i][j] = __builtin_amdgcn_mfma_f32_16x16x32_bf16(af[i][1], bfr[j][1], acc[qm][qn][i][j], 0, 0, 0); } \
    __builtin_amdgcn_s_setprio(0); } while (0)

  for (int kt = 0; kt < NT; ++kt) {
    const int bb = (kt & 1) << 16;
    const int ob = bb ^ 65536;
    const char* Lb = lds + bb;
#pragma unroll
    for (int i = 0; i < 4; ++i) {
      af[i][0] = *(const bf16x8*)(Lb + aoff0 + i * 2048);
      af[i][1] = *(const bf16x8*)(Lb + aoff1 + i * 2048);
    }
#pragma unroll
    for (int j = 0; j < 2; ++j) {
      bfr[j][0] = *(const bf16x8*)(Lb + 32768 + boff0 + j * 2048);
      bfr[j][1] = *(const bf16x8*)(Lb + 32768 + boff1 + j * 2048);
    }
    if (kt + 1 < NT) G2_STAGE_B0(ob, kt + 1);
    SBAR(); WAIT_LGKM0(); SCHED0();
    G2_MFMA(0, 0);
    SCHED0(); SBAR();
#pragma unroll
    for (int j = 0; j < 2; ++j) {
      bfr[j][0] = *(const bf16x8*)(Lb + 49152 + boff0 + j * 2048);
      bfr[j][1] = *(const bf16x8*)(Lb + 49152 + boff1 + j * 2048);
    }
    if (kt + 2 < NT) G2_STAGE_A0(bb, kt + 2);
    SBAR(); WAIT_LGKM0(); SCHED0();
    G2_MFMA(0, 1);
    SCHED0(); SBAR();
#pragma unroll
    for (int i = 0; i < 4; ++i) {
      af[i][0] = *(const bf16x8*)(Lb + 16384 + aoff0 + i * 2048);
      af[i][1] = *(const bf16x8*)(Lb + 16384 + aoff1 + i * 2048);
    }
    if (kt + 2 < NT) G2_STAGE_B1(bb, kt + 2);
    SBAR(); WAIT_LGKM0(); SCHED0();
    G2_MFMA(1, 1);
    SCHED0(); SBAR();
#pragma unroll
    for (int j = 0; j < 2; ++j) {
      bfr[j][0] = *(const bf16x8*)(Lb + 32768 + boff0 + j * 2048);
      bfr[j][1] = *(const bf16x8*)(Lb + 32768 + boff1 + j * 2048);
    }
    if (kt + 2 < NT) G2_STAGE_A1(bb, kt + 2);
    SBAR(); WAIT_LGKM0(); SCHED0();
    G2_MFMA(1, 0);
    SCHED0();
    if (kt + 2 < NT) { WAIT_VM6(); } else { WAIT_VM0(); }
    SBAR();
  }

#pragma unroll
  for (int qm = 0; qm < 2; ++qm)
#pragma unroll
    for (int qn = 0; qn < 2; ++qn)
#pragma unroll
      for (int i = 0; i < 4; ++i)
#pragma unroll
        for (int j = 0; j < 2; ++j)
#pragma unroll
          for (int r = 0; r < 4; ++r) {
            long m = m0 + qm * 128 + wm * 64 + i * 16 + lq * 4 + r;
            long nn = n0 + qn * 128 + wn * 32 + j * 16 + l16;
            C[m * HH + nn] = acc[qm][qn][i][j][r];
          }
#undef G2_STAGE_A0
#undef G2_STAGE_A1
#undef G2_STAGE_B0
#undef G2_STAGE_B1
#undef G2_MFMA
}

// =====================================================================
// GEMM1: inter = silu(X@gate^T)*(X@up^T) — 256x128 dual-B, 8-phase, XCD swz
// =====================================================================
__global__ __launch_bounds__(512, 2) void gemm1_8p_kernel(
    const unsigned short* __restrict__ X,
    const unsigned short* __restrict__ GU,
    unsigned short* __restrict__ inter) {
  extern __shared__ char lds[];
  const long K = HH;
  const int NT = (int)(K >> 6);
  const int tid = threadIdx.x;
  const int w = tid >> 6, l = tid & 63, l16 = l & 15, lq = l >> 4;
  const int wm = w >> 2, wn = w & 3;
  const int lin = blockIdx.y * 86 + blockIdx.x;      // nwg=1376, /8=172
  const int l2 = (lin & 7) * 172 + (lin >> 3);
  const long m0 = (long)(l2 / 86) * 256, n0 = (long)(l2 % 86) * 128;
  const int wb = w * 1024;

  const int srow = tid >> 3;
  const int sslot = (tid & 7) ^ (srow & 7);
  const unsigned short* sA00 = X + (m0 +       srow) * K + sslot * 8;
  const unsigned short* sA01 = X + (m0 +  64 + srow) * K + sslot * 8;
  const unsigned short* sA10 = X + (m0 + 128 + srow) * K + sslot * 8;
  const unsigned short* sA11 = X + (m0 + 192 + srow) * K + sslot * 8;
  const unsigned short* sBg0 = GU + (n0 +      srow) * K + sslot * 8;
  const unsigned short* sBg1 = GU + (n0 + 64 + srow) * K + sslot * 8;
  const unsigned short* sBu0 = GU + (II + n0 +      srow) * K + sslot * 8;
  const unsigned short* sBu1 = GU + (II + n0 + 64 + srow) * K + sslot * 8;

#define G1_STAGE_A0(bb, kt) do { \
    load_lds16(sA00 + (long)(kt) * 64, lds + (bb) + wb); \
    load_lds16(sA01 + (long)(kt) * 64, lds + (bb) + 8192 + wb); } while (0)
#define G1_STAGE_A1(bb, kt) do { \
    load_lds16(sA10 + (long)(kt) * 64, lds + (bb) + 16384 + wb); \
    load_lds16(sA11 + (long)(kt) * 64, lds + (bb) + 24576 + wb); } while (0)
#define G1_STAGE_B0(bb, kt) do { \
    load_lds16(sBg0 + (long)(kt) * 64, lds + (bb) + 32768 + wb); \
    load_lds16(sBu0 + (long)(kt) * 64, lds + (bb) + 49152 + wb); } while (0)
#define G1_STAGE_B1(bb, kt) do { \
    load_lds16(sBg1 + (long)(kt) * 64, lds + (bb) + 40960 + wb); \
    load_lds16(sBu1 + (long)(kt) * 64, lds + (bb) + 57344 + wb); } while (0)

  const int sw = l16 & 7;
  const int aoff0 = (wm * 64 + l16) * 128 + ((0 + lq) ^ sw) * 16;
  const int aoff1 = (wm * 64 + l16) * 128 + ((4 + lq) ^ sw) * 16;
  const int boff0 = (wn * 16 + l16) * 128 + ((0 + lq) ^ sw) * 16;
  const int boff1 = (wn * 16 + l16) * 128 + ((4 + lq) ^ sw) * 16;

  f32x4 ag[2][2][4], au[2][2][4];
#pragma unroll
  for (int qm = 0; qm < 2; ++qm)
#pragma unroll
    for (int qn = 0; qn < 2; ++qn)
#pragma unroll
      for (int i = 0; i < 4; ++i) { ag[qm][qn][i] = (f32x4)0.f; au[qm][qn][i] = (f32x4)0.f; }

  G1_STAGE_A0(0, 0); G1_STAGE_A1(0, 0); G1_STAGE_B0(0, 0); G1_STAGE_B1(0, 0);
  G1_STAGE_A0(65536, 1); G1_STAGE_B1(65536, 1); G1_STAGE_A1(65536, 1);
  WAIT_VM6();
  SBAR();

  bf16x8 af[4][2], bg[2], bu[2];
#define G1_MFMA(qm, qn) do { \
    __builtin_amdgcn_s_setprio(1); \
    _Pragma("unroll") for (int i = 0; i < 4; ++i) { \
      ag[qm][qn][i] = __builtin_amdgcn_mfma_f32_16x16x32_bf16(af[i][0], bg[0], ag[qm][qn][i], 0, 0, 0); \
      ag[qm][qn][i] = __builtin_amdgcn_mfma_f32_16x16x32_bf16(af[i][1], bg[1], ag[qm][qn][i], 0, 0, 0); \
      au[qm][qn][i] = __builtin_amdgcn_mfma_f32_16x16x32_bf16(af[i][0], bu[0], au[qm][qn][i], 0, 0, 0); \
      au[qm][qn][i] = __builtin_amdgcn_mfma_f32_16x16x32_bf16(af[i][1], bu[1], au[qm][qn][i], 0, 0, 0); } \
    __builtin_amdgcn_s_setprio(0); } while (0)

  for (int kt = 0; kt < NT; ++kt) {
    const int bb = (kt & 1) << 16;
    const int ob = bb ^ 65536;
    const char* Lb = lds + bb;
#pragma unroll
    for (int i = 0; i < 4; ++i) {
      af[i][0] = *(const bf16x8*)(Lb + aoff0 + i * 2048);
      af[i][1] = *(const bf16x8*)(Lb + aoff1 + i * 2048);
    }
    bg[0] = *(const bf16x8*)(Lb + 32768 + boff0);
    bg[1] = *(const bf16x8*)(Lb + 32768 + boff1);
    bu[0] = *(const bf16x8*)(Lb + 49152 + boff0);
    bu[1] = *(const bf16x8*)(Lb + 49152 + boff1);
    if (kt + 1 < NT) G1_STAGE_B0(ob, kt + 1);
    SBAR(); WAIT_LGKM0(); SCHED0();
    G1_MFMA(0, 0);
    SCHED0(); SBAR();
    bg[0] = *(const bf16x8*)(Lb + 40960 + boff0);
    bg[1] = *(const bf16x8*)(Lb + 40960 + boff1);
    bu[0] = *(const bf16x8*)(Lb + 57344 + boff0);
    bu[1] = *(const bf16x8*)(Lb + 57344 + boff1);
    if (kt + 2 < NT) G1_STAGE_A0(bb, kt + 2);
    SBAR(); WAIT_LGKM0(); SCHED0();
    G1_MFMA(0, 1);
    SCHED0(); SBAR();
#pragma unroll
    for (int i = 0; i < 4; ++i) {
      af[i][0] = *(const bf16x8*)(Lb + 16384 + aoff0 + i * 2048);
      af[i][1] = *(const bf16x8*)(Lb + 16384 + aoff1 + i * 2048);
    }
    if (kt + 2 < NT) G1_STAGE_B1(bb, kt + 2);
    SBAR(); WAIT_LGKM0(); SCHED0();
    G1_MFMA(1, 1);
    SCHED0(); SBAR();
    bg[0] = *(const bf16x8*)(Lb + 32768 + boff0);
    bg[1] = *(const bf16x8*)(Lb + 32768 + boff1);
    bu[0] = *(const bf16x8*)(Lb + 49152 + boff0);
    bu[1] = *(const bf16x8*)(Lb + 49152 + boff1);
    if (kt + 2 < NT) G1_STAGE_A1(bb, kt + 2);
    SBAR(); WAIT_LGKM0(); SCHED0();
    G1_MFMA(1, 0);
    SCHED0();
    if (kt + 2 < NT) { WAIT_VM6(); } else { WAIT_VM0(); }
    SBAR();
  }

#pragma unroll
  for (int qm = 0; qm < 2; ++qm)
#pragma unroll
    for (int qn = 0; qn < 2; ++qn)
#pragma unroll
      for (int i = 0; i < 4; ++i)
#pragma unroll
        for (int r = 0; r < 4; ++r) {
          long m = m0 + qm * 128 + wm * 64 + i * 16 + lq * 4 + r;
          long nn = n0 + qn * 64 + wn * 16 + l16;
          float g = ag[qm][qn][i][r], u = au[qm][qn][i][r];
          float sv = g / (1.f + __expf(-g));
          inter[m * II + nn] = f2bf(sv * u);
        }
#undef G1_STAGE_A0
#undef G1_STAGE_A1
#undef G1_STAGE_B0
#undef G1_STAGE_B1
#undef G1_MFMA
}

// ---------- launcher ----------
extern "C" void kernel_launch(void* const* d_in, const int* in_sizes, int n_in,
                              void* d_out, int out_size, void* d_ws, size_t ws_size,
                              hipStream_t stream) {
  const float* x   = (const float*)d_in[0];
  const float* guw = (const float*)d_in[1];
  const float* dww = (const float*)d_in[2];
  const float* rg  = (const float*)d_in[3];
  const float* ru  = (const float*)d_in[4];
  const float* rd  = (const float*)d_in[5];
  const float* fg  = (const float*)d_in[6];
  const float* fu  = (const float*)d_in[7];
  const float* fd  = (const float*)d_in[8];
  const float* sc  = (const float*)d_in[9];
  const int*   tix = (const int*)d_in[10];
  float* out = (float*)d_out;
  char* ws = (char*)d_ws;

  size_t o = 0;
  unsigned short* xb    = (unsigned short*)(ws + o); o += (size_t)TT * HH * 2;
  unsigned short* gub   = (unsigned short*)(ws + o); o += (size_t)2 * II * HH * 2;
  unsigned short* dwb   = (unsigned short*)(ws + o); o += (size_t)HH * II * 2;
  char* inter_base      = ws + o;                    o += (size_t)TT * II * 2;
  unsigned short* inter = (unsigned short*)inter_base;
  // alias into inter region (dead until gemm1 runs):
  unsigned short* wab   = (unsigned short*)inter_base;                    // 16.78 MB
  float* psum           = (float*)(inter_base + 16777216);                // 16.78 MB
  unsigned short* wdb   = (unsigned short*)(ws + o); o += (size_t)8 * HH * 128 * 2;
  unsigned short* irb   = (unsigned short*)(ws + o); o += (size_t)TT * 128 * 2;
  int* cntp             = (int*)(ws + o);            o += 256;
  int* offp             = (int*)(ws + o);            o += 256;
  int* listp            = (int*)(ws + o);            o += (size_t)TT * 4;

  hipFuncSetAttribute((const void*)gemm1_8p_kernel,
                      hipFuncAttributeMaxDynamicSharedMemorySize, 131072);
  hipFuncSetAttribute((const void*)gemm2_8p_kernel,
                      hipFuncAttributeMaxDynamicSharedMemorySize, 131072);
  hipFuncSetAttribute((const void*)adapter_psum_kernel,
                      hipFuncAttributeMaxDynamicSharedMemorySize, 81920);
  hipFuncSetAttribute((const void*)adapter_down2_kernel,
                      hipFuncAttributeMaxDynamicSharedMemorySize, 81920);

  cvt_bf16_kernel<<<2048, 256, 0, stream>>>(x, xb, TT * HH / 4);
  cvt_bf16_kernel<<<2048, 256, 0, stream>>>(guw, gub, 2 * II * HH / 4);
  cvt_bf16_kernel<<<2048, 256, 0, stream>>>(dww, dwb, HH * II / 4);
  cvt_wab_kernel<<<2048, 256, 0, stream>>>(rg, ru, fg, fu, wab);
  cvt_wdb_kernel<<<1024, 256, 0, stream>>>(rd, fd, wdb);
  bucket_kernel<<<1, 256, 0, stream>>>(tix, cntp, offp, listp);
  adapter_psum_kernel<<<dim3(NSLOT, 64, 4), 512, 81920, stream>>>(
      xb, wab, cntp, offp, listp, psum);
  adapter_reduce_kernel<<<2048, 256, 0, stream>>>(psum, sc, tix, irb);
  gemm1_8p_kernel<<<dim3(II / 128, TT / 256), 512, 131072, stream>>>(xb, gub, inter);
  gemm2_8p_kernel<<<dim3(HH / 256, TT / 256), 512, 131072, stream>>>(inter, dwb, out);
  adapter_down2_kernel<<<dim3(NSLOT, 64, 16), 512, 81920, stream>>>(
      irb, wdb, cntp, offp, listp, out);
}

// Round 5
// 1220.132 us; speedup vs baseline: 2.7425x; 1.0180x over previous
//
#include <hip/hip_runtime.h>
#include <hip/hip_bf16.h>

#define TT 4096L
#define HH 4096L
#define II 11008L
#define NSLOT 8

typedef short bf16x8 __attribute__((ext_vector_type(8)));
typedef float f32x4  __attribute__((ext_vector_type(4)));

#define WAIT_VM6() asm volatile("s_waitcnt vmcnt(6)" ::: "memory")
#define WAIT_VM0() asm volatile("s_waitcnt vmcnt(0)" ::: "memory")
#define SBAR() __builtin_amdgcn_s_barrier()
#define SCHED0() __builtin_amdgcn_sched_barrier(0)

__device__ __forceinline__ unsigned short f2bf(float v) {
  union { float f; unsigned int u; } c; c.f = v;
  unsigned int u = c.u;
  u += 0x7fffu + ((u >> 16) & 1u);
  return (unsigned short)(u >> 16);
}

__device__ __forceinline__ void load_lds16(const void* g, void* lds) {
  __builtin_amdgcn_global_load_lds(
      (const __attribute__((address_space(1))) unsigned int*)g,
      (__attribute__((address_space(3))) unsigned int*)lds, 16, 0, 0);
}

// ---------- fp32 -> bf16 convert ----------
__global__ __launch_bounds__(256) void cvt_bf16_kernel(
    const float* __restrict__ in, unsigned short* __restrict__ out, long n4) {
  long i = (long)blockIdx.x * blockDim.x + threadIdx.x;
  long stride = (long)gridDim.x * blockDim.x;
  for (; i < n4; i += stride) {
    float4 v = ((const float4*)in)[i];
    ushort4 o;
    o.x = f2bf(v.x); o.y = f2bf(v.y); o.z = f2bf(v.z); o.w = f2bf(v.w);
    ((ushort4*)out)[i] = o;
  }
}

// ---------- pack adapter up/gate weights: wab[s][256][H] bf16 ----------
__global__ __launch_bounds__(256) void cvt_wab_kernel(
    const float* __restrict__ rg, const float* __restrict__ ru,
    const float* __restrict__ fg, const float* __restrict__ fu,
    unsigned short* __restrict__ wab) {
  const long N4 = 8L * 256 * HH / 4;
  long i = (long)blockIdx.x * blockDim.x + threadIdx.x;
  long stride = (long)gridDim.x * blockDim.x;
  for (; i < N4; i += stride) {
    long grow = i >> 10;
    long q = i & 1023;
    int s = (int)(grow >> 8), r = (int)(grow & 255);
    const float* src;
    int rr = r & 63;
    if (r < 64) src = rg; else if (r < 128) src = ru;
    else if (r < 192) src = fg; else src = fu;
    float4 v = ((const float4*)src)[((long)s * 64 + rr) * 1024 + q];
    ushort4 o;
    o.x = f2bf(v.x); o.y = f2bf(v.y); o.z = f2bf(v.z); o.w = f2bf(v.w);
    ((ushort4*)wab)[i] = o;
  }
}

// ---------- pack adapter down weights: wdb[s][H][128] bf16 (rd|fd) ----------
__global__ __launch_bounds__(256) void cvt_wdb_kernel(
    const float* __restrict__ rd, const float* __restrict__ fd,
    unsigned short* __restrict__ wdb) {
  const long N4 = 8L * HH * 128 / 4;
  long i = (long)blockIdx.x * blockDim.x + threadIdx.x;
  long stride = (long)gridDim.x * blockDim.x;
  for (; i < N4; i += stride) {
    long rowg = i >> 5;
    int q = (int)(i & 31);
    float4 v;
    if (q < 16) v = ((const float4*)rd)[rowg * 16 + q];
    else        v = ((const float4*)fd)[rowg * 16 + (q - 16)];
    ushort4 o;
    o.x = f2bf(v.x); o.y = f2bf(v.y); o.z = f2bf(v.z); o.w = f2bf(v.w);
    ((ushort4*)wdb)[i] = o;
  }
}

// ---------- token bucketing ----------
__global__ __launch_bounds__(256) void bucket_kernel(
    const int* __restrict__ tix, int* __restrict__ cnt,
    int* __restrict__ off, int* __restrict__ list) {
  __shared__ int lc[NSLOT], lo[NSLOT], pc[NSLOT];
  int tid = threadIdx.x;
  if (tid < NSLOT) { lc[tid] = 0; pc[tid] = 0; }
  __syncthreads();
  for (int t = tid; t < TT; t += 256) atomicAdd(&lc[tix[t]], 1);
  __syncthreads();
  if (tid == 0) {
    int s = 0;
    for (int i = 0; i < NSLOT; ++i) { lo[i] = s; s += lc[i]; }
  }
  __syncthreads();
  for (int t = tid; t < TT; t += 256) {
    int s = tix[t];
    int p = atomicAdd(&pc[s], 1);
    list[lo[s] + p] = t;
  }
  if (tid < NSLOT) { cnt[tid] = lc[tid]; off[tid] = lo[tid]; }
}

// =====================================================================
// Adapter phase 1 (MFMA, split-K=4)
// =====================================================================
__global__ __launch_bounds__(512) void adapter_psum_kernel(
    const unsigned short* __restrict__ xb, const unsigned short* __restrict__ wab,
    const int* __restrict__ cnt, const int* __restrict__ off,
    const int* __restrict__ list, float* __restrict__ psum) {
  extern __shared__ char lds[];
  __shared__ int tl[64];
  int s = blockIdx.x, c = blockIdx.y, kq = blockIdx.z;
  int n = cnt[s];
  if (c * 64 >= n) return;
  int base = off[s] + c * 64;
  int ntok = min(64, n - c * 64);
  int tid = threadIdx.x;
  if (tid < 64) tl[tid] = (tid < ntok) ? list[base + tid] : list[base];
  __syncthreads();
  const int w = tid >> 6, l = tid & 63, l16 = l & 15, lq = l >> 4;
  const int sslot = (tid & 7) ^ ((tid >> 3) & 7);
  const long kbase = (long)kq * 1024;
  const unsigned short* xsrc = xb + (size_t)tl[tid >> 3] * HH + kbase + sslot * 8;
  const unsigned short* wsrc = wab + ((size_t)s * 256 + (tid >> 3)) * HH + kbase + sslot * 8;
  const int wdst = w * 1024;

#define PS_STAGE(buf, t) do { \
    load_lds16(xsrc + (long)(t) * 64, lds + (buf) + wdst); \
    _Pragma("unroll") for (int r = 0; r < 4; ++r) \
      load_lds16(wsrc + (size_t)(r * 64) * HH + (long)(t) * 64, \
                 lds + (buf) + 8192 + r * 8192 + wdst); } while (0)

  const int sw = l16 & 7;
  f32x4 acc[4][2];
#pragma unroll
  for (int i = 0; i < 4; ++i)
#pragma unroll
    for (int j = 0; j < 2; ++j) acc[i][j] = (f32x4)0.f;

  PS_STAGE(0, 0);
  __syncthreads();
  for (int t = 0; t < 16; ++t) {
    const int cb = (t & 1) * 40960;
    if (t + 1 < 16) PS_STAGE(cb ^ 40960, t + 1);
    const char* Lb = lds + cb;
    bf16x8 av[4][2], bv[2][2];
#pragma unroll
    for (int i = 0; i < 4; ++i)
#pragma unroll
      for (int kh = 0; kh < 2; ++kh)
        av[i][kh] = *(const bf16x8*)(Lb + (i * 16 + l16) * 128 + (((kh * 4 + lq) ^ sw) * 16));
#pragma unroll
    for (int j = 0; j < 2; ++j)
#pragma unroll
      for (int kh = 0; kh < 2; ++kh)
        bv[j][kh] = *(const bf16x8*)(Lb + 8192 + (w * 32 + j * 16 + l16) * 128 + (((kh * 4 + lq) ^ sw) * 16));
#pragma unroll
    for (int i = 0; i < 4; ++i)
#pragma unroll
      for (int j = 0; j < 2; ++j) {
        acc[i][j] = __builtin_amdgcn_mfma_f32_16x16x32_bf16(av[i][0], bv[j][0], acc[i][j], 0, 0, 0);
        acc[i][j] = __builtin_amdgcn_mfma_f32_16x16x32_bf16(av[i][1], bv[j][1], acc[i][j], 0, 0, 0);
      }
    __syncthreads();
  }
  float* pb = psum + (size_t)kq * TT * 256;
#pragma unroll
  for (int i = 0; i < 4; ++i)
#pragma unroll
    for (int j = 0; j < 2; ++j)
#pragma unroll
      for (int r = 0; r < 4; ++r) {
        int tk = i * 16 + lq * 4 + r;
        pb[(size_t)tl[tk] * 256 + w * 32 + j * 16 + l16] = acc[i][j][r];
      }
#undef PS_STAGE
}

// ---------- reduce split-K + SwiGLU + scale -> irb bf16 [T][128] ----------
__global__ __launch_bounds__(256) void adapter_reduce_kernel(
    const float* __restrict__ psum, const float* __restrict__ scales,
    const int* __restrict__ tix, unsigned short* __restrict__ irb) {
  int idx = blockIdx.x * 256 + threadIdx.x;
  int t = idx >> 7, n = idx & 127;
  int a = n >> 6, nn = n & 63;
  int cg = a ? 128 + nn : nn;
  size_t b = (size_t)t * 256;
  float g = 0.f, u = 0.f;
#pragma unroll
  for (int kq = 0; kq < 4; ++kq) {
    g += psum[(size_t)kq * TT * 256 + b + cg];
    u += psum[(size_t)kq * TT * 256 + b + cg + 64];
  }
  float sc = scales[tix[t] * 2 + a];
  float sv = g / (1.f + __expf(-g));
  irb[idx] = f2bf(sv * u * sc);
}

// =====================================================================
// Adapter phase 2 (MFMA): out[t][h] += irb[t][:] @ wdb[s][h][:]^T
// =====================================================================
__global__ __launch_bounds__(512) void adapter_down2_kernel(
    const unsigned short* __restrict__ irb, const unsigned short* __restrict__ wdb,
    const int* __restrict__ cnt, const int* __restrict__ off,
    const int* __restrict__ list, float* __restrict__ out) {
  extern __shared__ char lds[];
  __shared__ int tl[64];
  int s = blockIdx.x, c = blockIdx.y, hb = blockIdx.z;
  int n = cnt[s];
  if (c * 64 >= n) return;
  int base = off[s] + c * 64;
  int ntok = min(64, n - c * 64);
  int tid = threadIdx.x;
  if (tid < 64) tl[tid] = (tid < ntok) ? list[base + tid] : list[base];
  __syncthreads();
  const int w = tid >> 6, l = tid & 63, l16 = l & 15, lq = l >> 4;
  const int sslot = (tid & 15) ^ ((tid >> 4) & 15);
  const int wdst = w * 1024;
  const unsigned short* isrc0 = irb + (size_t)tl[tid >> 4] * 128 + sslot * 8;
  const unsigned short* isrc1 = irb + (size_t)tl[32 + (tid >> 4)] * 128 + sslot * 8;
  const unsigned short* wsrc =
      wdb + ((size_t)s * HH + hb * 256 + (tid >> 4)) * 128 + sslot * 8;
  load_lds16(isrc0, lds + wdst);
  load_lds16(isrc1, lds + 8192 + wdst);
#pragma unroll
  for (int r = 0; r < 8; ++r)
    load_lds16(wsrc + (size_t)r * 4096, lds + 16384 + r * 8192 + wdst);
  __syncthreads();

  f32x4 acc[4][2];
#pragma unroll
  for (int i = 0; i < 4; ++i)
#pragma unroll
    for (int j = 0; j < 2; ++j) acc[i][j] = (f32x4)0.f;

#pragma unroll
  for (int kf = 0; kf < 4; ++kf) {
    bf16x8 av[4], bv[2];
#pragma unroll
    for (int i = 0; i < 4; ++i)
      av[i] = *(const bf16x8*)(lds + (i * 16 + l16) * 256 + (((kf * 4 + lq) ^ l16) * 16));
#pragma unroll
    for (int j = 0; j < 2; ++j)
      bv[j] = *(const bf16x8*)(lds + 16384 + (w * 32 + j * 16 + l16) * 256 + (((kf * 4 + lq) ^ l16) * 16));
#pragma unroll
    for (int i = 0; i < 4; ++i)
#pragma unroll
      for (int j = 0; j < 2; ++j)
        acc[i][j] = __builtin_amdgcn_mfma_f32_16x16x32_bf16(av[i], bv[j], acc[i][j], 0, 0, 0);
  }
#pragma unroll
  for (int i = 0; i < 4; ++i)
#pragma unroll
    for (int j = 0; j < 2; ++j)
#pragma unroll
      for (int r = 0; r < 4; ++r) {
        int tk = i * 16 + lq * 4 + r;
        if (tk < ntok) {
          size_t o = (size_t)tl[tk] * HH + hb * 256 + w * 32 + j * 16 + l16;
          out[o] += acc[i][j][r];
        }
      }
}

// =====================================================================
// GEMM2: C = inter @ down_w^T — 256x256, BK=64, 8-phase, staggered frags.
// RACE-FIX vs r4: next-tile frag reads moved AFTER the post-vmcnt barrier
// (all waves' vmcnt(6) retire tile kt+1 loads before any wave reads them).
// =====================================================================
__global__ __launch_bounds__(512, 2) void gemm2_8p_kernel(
    const unsigned short* __restrict__ A,
    const unsigned short* __restrict__ B,
    float* __restrict__ C) {
  extern __shared__ char lds[];
  const long K = II;
  const int NT = (int)(K >> 6);
  const int tid = threadIdx.x;
  const int w = tid >> 6, l = tid & 63, l16 = l & 15, lq = l >> 4;
  const int wm = w >> 2, wn = w & 3;
  const int lin = blockIdx.y * 16 + blockIdx.x;      // nwg=256
  const int l2 = (lin & 7) * 32 + (lin >> 3);
  const long m0 = (long)(l2 >> 4) * 256, n0 = (long)(l2 & 15) * 256;
  const int wb = w * 1024;

  const int srow = tid >> 3;
  const int sslot = (tid & 7) ^ (srow & 7);
  const unsigned short* sA00 = A + (m0 +       srow) * K + sslot * 8;
  const unsigned short* sA01 = A + (m0 +  64 + srow) * K + sslot * 8;
  const unsigned short* sA10 = A + (m0 + 128 + srow) * K + sslot * 8;
  const unsigned short* sA11 = A + (m0 + 192 + srow) * K + sslot * 8;
  const unsigned short* sB00 = B + (n0 +       srow) * K + sslot * 8;
  const unsigned short* sB01 = B + (n0 +  64 + srow) * K + sslot * 8;
  const unsigned short* sB10 = B + (n0 + 128 + srow) * K + sslot * 8;
  const unsigned short* sB11 = B + (n0 + 192 + srow) * K + sslot * 8;

#define G2_STAGE_A0(bb, kt) do { \
    load_lds16(sA00 + (long)(kt) * 64, lds + (bb) + wb); \
    load_lds16(sA01 + (long)(kt) * 64, lds + (bb) + 8192 + wb); } while (0)
#define G2_STAGE_A1(bb, kt) do { \
    load_lds16(sA10 + (long)(kt) * 64, lds + (bb) + 16384 + wb); \
    load_lds16(sA11 + (long)(kt) * 64, lds + (bb) + 24576 + wb); } while (0)
#define G2_STAGE_B0(bb, kt) do { \
    load_lds16(sB00 + (long)(kt) * 64, lds + (bb) + 32768 + wb); \
    load_lds16(sB01 + (long)(kt) * 64, lds + (bb) + 40960 + wb); } while (0)
#define G2_STAGE_B1(bb, kt) do { \
    load_lds16(sB10 + (long)(kt) * 64, lds + (bb) + 49152 + wb); \
    load_lds16(sB11 + (long)(kt) * 64, lds + (bb) + 57344 + wb); } while (0)

  const int sw = l16 & 7;
  const int aoff0 = (wm * 64 + l16) * 128 + ((0 + lq) ^ sw) * 16;
  const int aoff1 = (wm * 64 + l16) * 128 + ((4 + lq) ^ sw) * 16;
  const int boff0 = (wn * 32 + l16) * 128 + ((0 + lq) ^ sw) * 16;
  const int boff1 = (wn * 32 + l16) * 128 + ((4 + lq) ^ sw) * 16;

  f32x4 acc[2][2][4][2];
#pragma unroll
  for (int qm = 0; qm < 2; ++qm)
#pragma unroll
    for (int qn = 0; qn < 2; ++qn)
#pragma unroll
      for (int i = 0; i < 4; ++i)
#pragma unroll
        for (int j = 0; j < 2; ++j) acc[qm][qn][i][j] = (f32x4)0.f;

  // prologue: tile0 all; tile1 A0,B1,A1
  G2_STAGE_A0(0, 0); G2_STAGE_A1(0, 0); G2_STAGE_B0(0, 0); G2_STAGE_B1(0, 0);
  G2_STAGE_A0(65536, 1); G2_STAGE_B1(65536, 1); G2_STAGE_A1(65536, 1);
  WAIT_VM6();
  SBAR();

  bf16x8 af[4][2], b0v[2][2], b1v[2][2];
  // pre-read A0(0), B0(0) frags (safe: post-barrier, all waves retired tile0)
#pragma unroll
  for (int i = 0; i < 4; ++i) {
    af[i][0] = *(const bf16x8*)(lds + aoff0 + i * 2048);
    af[i][1] = *(const bf16x8*)(lds + aoff1 + i * 2048);
  }
#pragma unroll
  for (int j = 0; j < 2; ++j) {
    b0v[j][0] = *(const bf16x8*)(lds + 32768 + boff0 + j * 2048);
    b0v[j][1] = *(const bf16x8*)(lds + 32768 + boff1 + j * 2048);
  }

#define G2_MFMA(qm, qn, bset) do { \
    __builtin_amdgcn_s_setprio(1); \
    _Pragma("unroll") for (int i = 0; i < 4; ++i) \
      _Pragma("unroll") for (int j = 0; j < 2; ++j) { \
        acc[qm][qn][i][j] = __builtin_amdgcn_mfma_f32_16x16x32_bf16(af[i][0], bset[j][0], acc[qm][qn][i][j], 0, 0, 0); \
        acc[qm][qn][i][j] = __builtin_amdgcn_mfma_f32_16x16x32_bf16(af[i][1], bset[j][1], acc[qm][qn][i][j], 0, 0, 0); } \
    __builtin_amdgcn_s_setprio(0); } while (0)

  for (int kt = 0; kt < NT; ++kt) {
    const int bb = (kt & 1) << 16;
    const int ob = bb ^ 65536;
    const char* Lb = lds + bb;
    // P0: pre-read B1 frags; stage B0(kt+1); MFMA Q00(A0,B0)
#pragma unroll
    for (int j = 0; j < 2; ++j) {
      b1v[j][0] = *(const bf16x8*)(Lb + 49152 + boff0 + j * 2048);
      b1v[j][1] = *(const bf16x8*)(Lb + 49152 + boff1 + j * 2048);
    }
    if (kt + 1 < NT) G2_STAGE_B0(ob, kt + 1);
    SBAR(); SCHED0();
    G2_MFMA(0, 0, b0v);
    SCHED0(); SBAR();
    // P1: stage A0(kt+2); MFMA Q01(A0,B1); post-read A1 frags
    if (kt + 2 < NT) G2_STAGE_A0(bb, kt + 2);
    SBAR(); SCHED0();
    G2_MFMA(0, 1, b1v);
    SCHED0();
#pragma unroll
    for (int i = 0; i < 4; ++i) {
      af[i][0] = *(const bf16x8*)(Lb + 16384 + aoff0 + i * 2048);
      af[i][1] = *(const bf16x8*)(Lb + 16384 + aoff1 + i * 2048);
    }
    SBAR();
    // P2: stage B1(kt+2); MFMA Q11(A1,B1)
    if (kt + 2 < NT) G2_STAGE_B1(bb, kt + 2);
    SBAR(); SCHED0();
    G2_MFMA(1, 1, b1v);
    SCHED0(); SBAR();
    // P3: stage A1(kt+2); MFMA Q10(A1,B0); vmcnt; BARRIER; then next-tile reads
    if (kt + 2 < NT) G2_STAGE_A1(bb, kt + 2);
    SBAR(); SCHED0();
    G2_MFMA(1, 0, b0v);
    SCHED0();
    if (kt + 2 < NT) { WAIT_VM6(); } else { WAIT_VM0(); }
    SBAR();   // all waves retired their tile-(kt+1) loads -> region fully landed
    if (kt + 1 < NT) {
      const char* Lo = lds + ob;
#pragma unroll
      for (int i = 0; i < 4; ++i) {
        af[i][0] = *(const bf16x8*)(Lo + aoff0 + i * 2048);
        af[i][1] = *(const bf16x8*)(Lo + aoff1 + i * 2048);
      }
#pragma unroll
      for (int j = 0; j < 2; ++j) {
        b0v[j][0] = *(const bf16x8*)(Lo + 32768 + boff0 + j * 2048);
        b0v[j][1] = *(const bf16x8*)(Lo + 32768 + boff1 + j * 2048);
      }
    }
  }

#pragma unroll
  for (int qm = 0; qm < 2; ++qm)
#pragma unroll
    for (int qn = 0; qn < 2; ++qn)
#pragma unroll
      for (int i = 0; i < 4; ++i)
#pragma unroll
        for (int j = 0; j < 2; ++j)
#pragma unroll
          for (int r = 0; r < 4; ++r) {
            long m = m0 + qm * 128 + wm * 64 + i * 16 + lq * 4 + r;
            long nn = n0 + qn * 128 + wn * 32 + j * 16 + l16;
            C[m * HH + nn] = acc[qm][qn][i][j][r];
          }
#undef G2_STAGE_A0
#undef G2_STAGE_A1
#undef G2_STAGE_B0
#undef G2_STAGE_B1
#undef G2_MFMA
}

// =====================================================================
// GEMM1: inter = silu(X@gate^T)*(X@up^T) — 256x128 dual-B, staggered frags,
// same race-fix as gemm2.
// =====================================================================
__global__ __launch_bounds__(512, 2) void gemm1_8p_kernel(
    const unsigned short* __restrict__ X,
    const unsigned short* __restrict__ GU,
    unsigned short* __restrict__ inter) {
  extern __shared__ char lds[];
  const long K = HH;
  const int NT = (int)(K >> 6);
  const int tid = threadIdx.x;
  const int w = tid >> 6, l = tid & 63, l16 = l & 15, lq = l >> 4;
  const int wm = w >> 2, wn = w & 3;
  const int lin = blockIdx.y * 86 + blockIdx.x;      // nwg=1376
  const int l2 = (lin & 7) * 172 + (lin >> 3);
  const long m0 = (long)(l2 / 86) * 256, n0 = (long)(l2 % 86) * 128;
  const int wb = w * 1024;

  const int srow = tid >> 3;
  const int sslot = (tid & 7) ^ (srow & 7);
  const unsigned short* sA00 = X + (m0 +       srow) * K + sslot * 8;
  const unsigned short* sA01 = X + (m0 +  64 + srow) * K + sslot * 8;
  const unsigned short* sA10 = X + (m0 + 128 + srow) * K + sslot * 8;
  const unsigned short* sA11 = X + (m0 + 192 + srow) * K + sslot * 8;
  const unsigned short* sBg0 = GU + (n0 +      srow) * K + sslot * 8;
  const unsigned short* sBg1 = GU + (n0 + 64 + srow) * K + sslot * 8;
  const unsigned short* sBu0 = GU + (II + n0 +      srow) * K + sslot * 8;
  const unsigned short* sBu1 = GU + (II + n0 + 64 + srow) * K + sslot * 8;

#define G1_STAGE_A0(bb, kt) do { \
    load_lds16(sA00 + (long)(kt) * 64, lds + (bb) + wb); \
    load_lds16(sA01 + (long)(kt) * 64, lds + (bb) + 8192 + wb); } while (0)
#define G1_STAGE_A1(bb, kt) do { \
    load_lds16(sA10 + (long)(kt) * 64, lds + (bb) + 16384 + wb); \
    load_lds16(sA11 + (long)(kt) * 64, lds + (bb) + 24576 + wb); } while (0)
#define G1_STAGE_B0(bb, kt) do { \
    load_lds16(sBg0 + (long)(kt) * 64, lds + (bb) + 32768 + wb); \
    load_lds16(sBu0 + (long)(kt) * 64, lds + (bb) + 49152 + wb); } while (0)
#define G1_STAGE_B1(bb, kt) do { \
    load_lds16(sBg1 + (long)(kt) * 64, lds + (bb) + 40960 + wb); \
    load_lds16(sBu1 + (long)(kt) * 64, lds + (bb) + 57344 + wb); } while (0)

  const int sw = l16 & 7;
  const int aoff0 = (wm * 64 + l16) * 128 + ((0 + lq) ^ sw) * 16;
  const int aoff1 = (wm * 64 + l16) * 128 + ((4 + lq) ^ sw) * 16;
  const int boff0 = (wn * 16 + l16) * 128 + ((0 + lq) ^ sw) * 16;
  const int boff1 = (wn * 16 + l16) * 128 + ((4 + lq) ^ sw) * 16;

  f32x4 ag[2][2][4], au[2][2][4];
#pragma unroll
  for (int qm = 0; qm < 2; ++qm)
#pragma unroll
    for (int qn = 0; qn < 2; ++qn)
#pragma unroll
      for (int i = 0; i < 4; ++i) { ag[qm][qn][i] = (f32x4)0.f; au[qm][qn][i] = (f32x4)0.f; }

  G1_STAGE_A0(0, 0); G1_STAGE_A1(0, 0); G1_STAGE_B0(0, 0); G1_STAGE_B1(0, 0);
  G1_STAGE_A0(65536, 1); G1_STAGE_B1(65536, 1); G1_STAGE_A1(65536, 1);
  WAIT_VM6();
  SBAR();

  bf16x8 af[4][2], b0g[2], b0u[2], b1g[2], b1u[2];
#pragma unroll
  for (int i = 0; i < 4; ++i) {
    af[i][0] = *(const bf16x8*)(lds + aoff0 + i * 2048);
    af[i][1] = *(const bf16x8*)(lds + aoff1 + i * 2048);
  }
  b0g[0] = *(const bf16x8*)(lds + 32768 + boff0);
  b0g[1] = *(const bf16x8*)(lds + 32768 + boff1);
  b0u[0] = *(const bf16x8*)(lds + 49152 + boff0);
  b0u[1] = *(const bf16x8*)(lds + 49152 + boff1);

#define G1_MFMA(qm, qn, bgs, bus) do { \
    __builtin_amdgcn_s_setprio(1); \
    _Pragma("unroll") for (int i = 0; i < 4; ++i) { \
      ag[qm][qn][i] = __builtin_amdgcn_mfma_f32_16x16x32_bf16(af[i][0], bgs[0], ag[qm][qn][i], 0, 0, 0); \
      ag[qm][qn][i] = __builtin_amdgcn_mfma_f32_16x16x32_bf16(af[i][1], bgs[1], ag[qm][qn][i], 0, 0, 0); \
      au[qm][qn][i] = __builtin_amdgcn_mfma_f32_16x16x32_bf16(af[i][0], bus[0], au[qm][qn][i], 0, 0, 0); \
      au[qm][qn][i] = __builtin_amdgcn_mfma_f32_16x16x32_bf16(af[i][1], bus[1], au[qm][qn][i], 0, 0, 0); } \
    __builtin_amdgcn_s_setprio(0); } while (0)

  for (int kt = 0; kt < NT; ++kt) {
    const int bb = (kt & 1) << 16;
    const int ob = bb ^ 65536;
    const char* Lb = lds + bb;
    // P0: pre-read B1 frags; stage B0(kt+1); MFMA Q00
    b1g[0] = *(const bf16x8*)(Lb + 40960 + boff0);
    b1g[1] = *(const bf16x8*)(Lb + 40960 + boff1);
    b1u[0] = *(const bf16x8*)(Lb + 57344 + boff0);
    b1u[1] = *(const bf16x8*)(Lb + 57344 + boff1);
    if (kt + 1 < NT) G1_STAGE_B0(ob, kt + 1);
    SBAR(); SCHED0();
    G1_MFMA(0, 0, b0g, b0u);
    SCHED0(); SBAR();
    // P1: stage A0(kt+2); MFMA Q01; post-read A1 frags
    if (kt + 2 < NT) G1_STAGE_A0(bb, kt + 2);
    SBAR(); SCHED0();
    G1_MFMA(0, 1, b1g, b1u);
    SCHED0();
#pragma unroll
    for (int i = 0; i < 4; ++i) {
      af[i][0] = *(const bf16x8*)(Lb + 16384 + aoff0 + i * 2048);
      af[i][1] = *(const bf16x8*)(Lb + 16384 + aoff1 + i * 2048);
    }
    SBAR();
    // P2: stage B1(kt+2); MFMA Q11
    if (kt + 2 < NT) G1_STAGE_B1(bb, kt + 2);
    SBAR(); SCHED0();
    G1_MFMA(1, 1, b1g, b1u);
    SCHED0(); SBAR();
    // P3: stage A1(kt+2); MFMA Q10; vmcnt; BARRIER; next-tile reads
    if (kt + 2 < NT) G1_STAGE_A1(bb, kt + 2);
    SBAR(); SCHED0();
    G1_MFMA(1, 0, b0g, b0u);
    SCHED0();
    if (kt + 2 < NT) { WAIT_VM6(); } else { WAIT_VM0(); }
    SBAR();   // race-fix: all waves' tile-(kt+1) loads retired before reads
    if (kt + 1 < NT) {
      const char* Lo = lds + ob;
#pragma unroll
      for (int i = 0; i < 4; ++i) {
        af[i][0] = *(const bf16x8*)(Lo + aoff0 + i * 2048);
        af[i][1] = *(const bf16x8*)(Lo + aoff1 + i * 2048);
      }
      b0g[0] = *(const bf16x8*)(Lo + 32768 + boff0);
      b0g[1] = *(const bf16x8*)(Lo + 32768 + boff1);
      b0u[0] = *(const bf16x8*)(Lo + 49152 + boff0);
      b0u[1] = *(const bf16x8*)(Lo + 49152 + boff1);
    }
  }

#pragma unroll
  for (int qm = 0; qm < 2; ++qm)
#pragma unroll
    for (int qn = 0; qn < 2; ++qn)
#pragma unroll
      for (int i = 0; i < 4; ++i)
#pragma unroll
        for (int r = 0; r < 4; ++r) {
          long m = m0 + qm * 128 + wm * 64 + i * 16 + lq * 4 + r;
          long nn = n0 + qn * 64 + wn * 16 + l16;
          float g = ag[qm][qn][i][r], u = au[qm][qn][i][r];
          float sv = g / (1.f + __expf(-g));
          inter[m * II + nn] = f2bf(sv * u);
        }
#undef G1_STAGE_A0
#undef G1_STAGE_A1
#undef G1_STAGE_B0
#undef G1_STAGE_B1
#undef G1_MFMA
}

// ---------- launcher ----------
extern "C" void kernel_launch(void* const* d_in, const int* in_sizes, int n_in,
                              void* d_out, int out_size, void* d_ws, size_t ws_size,
                              hipStream_t stream) {
  const float* x   = (const float*)d_in[0];
  const float* guw = (const float*)d_in[1];
  const float* dww = (const float*)d_in[2];
  const float* rg  = (const float*)d_in[3];
  const float* ru  = (const float*)d_in[4];
  const float* rd  = (const float*)d_in[5];
  const float* fg  = (const float*)d_in[6];
  const float* fu  = (const float*)d_in[7];
  const float* fd  = (const float*)d_in[8];
  const float* sc  = (const float*)d_in[9];
  const int*   tix = (const int*)d_in[10];
  float* out = (float*)d_out;
  char* ws = (char*)d_ws;

  size_t o = 0;
  unsigned short* xb    = (unsigned short*)(ws + o); o += (size_t)TT * HH * 2;
  unsigned short* gub   = (unsigned short*)(ws + o); o += (size_t)2 * II * HH * 2;
  unsigned short* dwb   = (unsigned short*)(ws + o); o += (size_t)HH * II * 2;
  char* inter_base      = ws + o;                    o += (size_t)TT * II * 2;
  unsigned short* inter = (unsigned short*)inter_base;
  unsigned short* wab   = (unsigned short*)inter_base;
  float* psum           = (float*)(inter_base + 16777216);
  unsigned short* wdb   = (unsigned short*)(ws + o); o += (size_t)8 * HH * 128 * 2;
  unsigned short* irb   = (unsigned short*)(ws + o); o += (size_t)TT * 128 * 2;
  int* cntp             = (int*)(ws + o);            o += 256;
  int* offp             = (int*)(ws + o);            o += 256;
  int* listp            = (int*)(ws + o);            o += (size_t)TT * 4;

  hipFuncSetAttribute((const void*)gemm1_8p_kernel,
                      hipFuncAttributeMaxDynamicSharedMemorySize, 131072);
  hipFuncSetAttribute((const void*)gemm2_8p_kernel,
                      hipFuncAttributeMaxDynamicSharedMemorySize, 131072);
  hipFuncSetAttribute((const void*)adapter_psum_kernel,
                      hipFuncAttributeMaxDynamicSharedMemorySize, 81920);
  hipFuncSetAttribute((const void*)adapter_down2_kernel,
                      hipFuncAttributeMaxDynamicSharedMemorySize, 81920);

  cvt_bf16_kernel<<<2048, 256, 0, stream>>>(x, xb, TT * HH / 4);
  cvt_bf16_kernel<<<2048, 256, 0, stream>>>(guw, gub, 2 * II * HH / 4);
  cvt_bf16_kernel<<<2048, 256, 0, stream>>>(dww, dwb, HH * II / 4);
  cvt_wab_kernel<<<2048, 256, 0, stream>>>(rg, ru, fg, fu, wab);
  cvt_wdb_kernel<<<1024, 256, 0, stream>>>(rd, fd, wdb);
  bucket_kernel<<<1, 256, 0, stream>>>(tix, cntp, offp, listp);
  adapter_psum_kernel<<<dim3(NSLOT, 64, 4), 512, 81920, stream>>>(
      xb, wab, cntp, offp, listp, psum);
  adapter_reduce_kernel<<<2048, 256, 0, stream>>>(psum, sc, tix, irb);
  gemm1_8p_kernel<<<dim3(II / 128, TT / 256), 512, 131072, stream>>>(xb, gub, inter);
  gemm2_8p_kernel<<<dim3(HH / 256, TT / 256), 512, 131072, stream>>>(inter, dwb, out);
  adapter_down2_kernel<<<dim3(NSLOT, 64, 16), 512, 81920, stream>>>(
      irb, wdb, cntp, offp, listp, out);
}